// Round 1
// baseline (15639.087 us; speedup 1.0000x reference)
//
#include <hip/hip_runtime.h>

#define NN 100000
#define HH 150
#define SP 152      // padded row stride (floats), 608B = 16B-aligned
#define EE 500000
#define GG 16
#define NPASS 4

static __device__ __forceinline__ float dot4(float4 a, float4 b, float acc) {
    acc = fmaf(a.x, b.x, acc);
    acc = fmaf(a.y, b.y, acc);
    acc = fmaf(a.z, b.z, acc);
    acc = fmaf(a.w, b.w, acc);
    return acc;
}

// ---------- init: restride nodes (N x 150) -> h (N x 152, pad zeroed) ----------
__global__ void k_init(const float* __restrict__ nodes, float* __restrict__ h) {
    int idx = blockIdx.x * 256 + threadIdx.x;
    if (idx >= NN * SP) return;
    int i = idx / SP, c = idx - i * SP;
    h[idx] = (c < HH) ? nodes[i * HH + c] : 0.f;
}

// ---------- weight pad-copy: src rows x K -> dst rows x SP (dst pre-zeroed) ----------
__global__ void k_pad(const float* __restrict__ s, float* __restrict__ d, int rows, int K) {
    int idx = blockIdx.x * 256 + threadIdx.x;
    if (idx >= rows * K) return;
    int r = idx / K, c = idx - r * K;
    d[r * SP + c] = s[idx];
}

// ---------- CSR build ----------
__global__ void k_hist(const int* __restrict__ edges, int* __restrict__ cnt) {
    int e = blockIdx.x * 256 + threadIdx.x;
    if (e >= EE) return;
    atomicAdd(&cnt[edges[2 * e]], 1);   // dst = e[:,0]
}

__global__ __launch_bounds__(1024) void k_scan(const int* __restrict__ cnt,
                                               int* __restrict__ off, int* __restrict__ cur) {
    __shared__ int sd[1024];
    __shared__ int s_run;
    int t = threadIdx.x;
    if (t == 0) s_run = 0;
    __syncthreads();
    for (int base = 0; base < NN; base += 8192) {
        int i0 = base + t * 8;
        int v[8]; int s = 0;
#pragma unroll
        for (int u = 0; u < 8; u++) { int i = i0 + u; v[u] = (i < NN) ? cnt[i] : 0; s += v[u]; }
        sd[t] = s;
        __syncthreads();
        int runbase = s_run;
        for (int ofs = 1; ofs < 1024; ofs <<= 1) {
            int y = 0;
            if (t >= ofs) y = sd[t - ofs];
            __syncthreads();
            if (t >= ofs) sd[t] += y;
            __syncthreads();
        }
        int excl = runbase + sd[t] - s;
#pragma unroll
        for (int u = 0; u < 8; u++) {
            int i = i0 + u;
            if (i < NN) { off[i] = excl; cur[i] = excl; excl += v[u]; }
        }
        __syncthreads();
        if (t == 1023) s_run = runbase + sd[1023];
        __syncthreads();
    }
    if (t == 0) off[NN] = s_run;
}

__global__ void k_fill(const int* __restrict__ edges, int* __restrict__ cur, int* __restrict__ csr) {
    int e = blockIdx.x * 256 + threadIdx.x;
    if (e >= EE) return;
    int dst = edges[2 * e], src = edges[2 * e + 1];
    int pos = atomicAdd(&cur[dst], 1);
    csr[pos] = src;
}

// ---------- fused 2-layer edge-MLP per node: msg = lrelu(h@W1^T+b1)@W2^T+b2 ----------
// block 256 = 16x16, BM=64 rows, j-tiles of 64 (x3 covers 150 padded to 192 W rows)
__global__ __launch_bounds__(256) void k_msg(const float* __restrict__ h,
                                             const float* __restrict__ W1p, const float* __restrict__ b1,
                                             const float* __restrict__ W2p, const float* __restrict__ b2,
                                             float* __restrict__ msg) {
    __shared__ float4 AL[64 * 38];
    int tid = threadIdx.x, tx = tid & 15, ty = tid >> 4;
    int m0 = blockIdx.x * 64;
    for (int idx = tid; idx < 64 * 38; idx += 256) {
        int r = idx / 38, c = idx - r * 38;
        int row = m0 + r;
        float4 v = make_float4(0.f, 0.f, 0.f, 0.f);
        if (row < NN) v = ((const float4*)(h + (size_t)row * SP))[c];
        AL[idx] = v;
    }
    __syncthreads();
    const float4* W1v = (const float4*)W1p;
    float tmp[3][4][4];
#pragma unroll
    for (int jt = 0; jt < 3; jt++) {
        float acc[4][4] = {};
        int j0 = jt * 64 + tx * 4;
#pragma unroll 2
        for (int k4 = 0; k4 < 38; k4++) {
            float4 a0 = AL[(ty * 4 + 0) * 38 + k4];
            float4 a1 = AL[(ty * 4 + 1) * 38 + k4];
            float4 a2 = AL[(ty * 4 + 2) * 38 + k4];
            float4 a3 = AL[(ty * 4 + 3) * 38 + k4];
#pragma unroll
            for (int jj = 0; jj < 4; jj++) {
                float4 w = W1v[(j0 + jj) * 38 + k4];
                acc[0][jj] = dot4(a0, w, acc[0][jj]);
                acc[1][jj] = dot4(a1, w, acc[1][jj]);
                acc[2][jj] = dot4(a2, w, acc[2][jj]);
                acc[3][jj] = dot4(a3, w, acc[3][jj]);
            }
        }
#pragma unroll
        for (int jj = 0; jj < 4; jj++) {
            int j = j0 + jj;
            float bb = b1[j < HH ? j : HH - 1];
#pragma unroll
            for (int mm = 0; mm < 4; mm++) {
                float v = acc[mm][jj] + bb;
                tmp[jt][mm][jj] = v > 0.f ? v : 0.01f * v;
            }
        }
    }
    __syncthreads();
    float* ALs = (float*)AL;
#pragma unroll
    for (int jt = 0; jt < 3; jt++)
#pragma unroll
        for (int mm = 0; mm < 4; mm++)
#pragma unroll
            for (int jj = 0; jj < 4; jj++) {
                int j = jt * 64 + tx * 4 + jj;
                if (j < SP) ALs[(ty * 4 + mm) * SP + j] = tmp[jt][mm][jj];
            }
    __syncthreads();
    const float4* W2v = (const float4*)W2p;
#pragma unroll
    for (int jt = 0; jt < 3; jt++) {
        float acc[4][4] = {};
        int j0 = jt * 64 + tx * 4;
#pragma unroll 2
        for (int k4 = 0; k4 < 38; k4++) {
            float4 a0 = AL[(ty * 4 + 0) * 38 + k4];
            float4 a1 = AL[(ty * 4 + 1) * 38 + k4];
            float4 a2 = AL[(ty * 4 + 2) * 38 + k4];
            float4 a3 = AL[(ty * 4 + 3) * 38 + k4];
#pragma unroll
            for (int jj = 0; jj < 4; jj++) {
                float4 w = W2v[(j0 + jj) * 38 + k4];
                acc[0][jj] = dot4(a0, w, acc[0][jj]);
                acc[1][jj] = dot4(a1, w, acc[1][jj]);
                acc[2][jj] = dot4(a2, w, acc[2][jj]);
                acc[3][jj] = dot4(a3, w, acc[3][jj]);
            }
        }
#pragma unroll
        for (int mm = 0; mm < 4; mm++) {
            int row = m0 + ty * 4 + mm;
            if (row >= NN) continue;
            if (j0 + 3 < HH) {
                float4 o = make_float4(acc[mm][0] + b2[j0], acc[mm][1] + b2[j0 + 1],
                                       acc[mm][2] + b2[j0 + 2], acc[mm][3] + b2[j0 + 3]);
                ((float4*)(msg + (size_t)row * SP))[j0 >> 2] = o;
            } else {
#pragma unroll
                for (int jj = 0; jj < 4; jj++) {
                    int j = j0 + jj;
                    if (j < HH) msg[(size_t)row * SP + j] = acc[mm][jj] + b2[j];
                }
            }
        }
    }
}

// ---------- gather: incoming[d] (+)= sum_{e in CSR[d]} msg[src[e]] ----------
__global__ void k_gather(const float* __restrict__ msg, const int* __restrict__ off,
                         const int* __restrict__ csr, float* __restrict__ inc, int add) {
    int d = blockIdx.x * 4 + (threadIdx.x >> 6);
    int lane = threadIdx.x & 63;
    if (d >= NN) return;
    int e0 = off[d], e1 = off[d + 1];
    float a0 = 0.f, a1 = 0.f, a2 = 0.f;
    for (int e = e0; e < e1; e++) {
        int s = csr[e];
        const float* mr = msg + (size_t)s * SP;
        a0 += mr[lane];
        a1 += mr[lane + 64];
        if (lane < 22) a2 += mr[lane + 128];
    }
    float* ir = inc + (size_t)d * SP;
    if (add) {
        a0 += ir[lane]; a1 += ir[lane + 64];
        if (lane < 22) a2 += ir[lane + 128];
    }
    ir[lane] = a0; ir[lane + 64] = a1;
    if (lane < 22) ir[lane + 128] = a2;
}

// ---------- fused GRU: h_new = GRU(incoming, h) ----------
// grid (ceil(N/64), 3): BM=64 rows, 64-wide output column chunk jc
__global__ __launch_bounds__(256) void k_gru(const float* __restrict__ inc, const float* __restrict__ hold,
                                             const float* __restrict__ Wihp, const float* __restrict__ bih,
                                             const float* __restrict__ Whhp, const float* __restrict__ bhh,
                                             float* __restrict__ hnew) {
    __shared__ float4 IL[64 * 38];
    int tid = threadIdx.x, tx = tid & 15, ty = tid >> 4;
    int m0 = blockIdx.x * 64;
    int jc = blockIdx.y;
    for (int idx = tid; idx < 64 * 38; idx += 256) {
        int r = idx / 38, c = idx - r * 38;
        int row = m0 + r;
        float4 v = make_float4(0.f, 0.f, 0.f, 0.f);
        if (row < NN) v = ((const float4*)(inc + (size_t)row * SP))[c];
        IL[idx] = v;
    }
    __syncthreads();
    int j0 = jc * 64 + tx * 4;
    const float4* Wiv = (const float4*)Wihp;
    const float4* Whv = (const float4*)Whhp;
    const float4* hr4[4];
#pragma unroll
    for (int mm = 0; mm < 4; mm++) {
        int row = m0 + ty * 4 + mm;
        if (row >= NN) row = NN - 1;
        hr4[mm] = (const float4*)(hold + (size_t)row * SP);
    }
    float aI[3][4][4] = {};
    float aH[3][4][4] = {};
    for (int k4 = 0; k4 < 38; k4++) {
        float4 xi[4], xh[4];
#pragma unroll
        for (int mm = 0; mm < 4; mm++) {
            xi[mm] = IL[(ty * 4 + mm) * 38 + k4];
            xh[mm] = hr4[mm][k4];
        }
#pragma unroll
        for (int g = 0; g < 3; g++) {
#pragma unroll
            for (int jj = 0; jj < 4; jj++) {
                int wr = g * HH + j0 + jj;   // padded weight buffers have 512 zeroed rows
                float4 wi = Wiv[wr * 38 + k4];
                float4 wh = Whv[wr * 38 + k4];
#pragma unroll
                for (int mm = 0; mm < 4; mm++) {
                    aI[g][mm][jj] = dot4(xi[mm], wi, aI[g][mm][jj]);
                    aH[g][mm][jj] = dot4(xh[mm], wh, aH[g][mm][jj]);
                }
            }
        }
    }
#pragma unroll
    for (int mm = 0; mm < 4; mm++) {
        int row = m0 + ty * 4 + mm;
        if (row >= NN) continue;
#pragma unroll
        for (int jj = 0; jj < 4; jj++) {
            int jy = j0 + jj;
            if (jy >= HH) continue;
            float ir = aI[0][mm][jj] + bih[jy];
            float hr = aH[0][mm][jj] + bhh[jy];
            float iz = aI[1][mm][jj] + bih[HH + jy];
            float hz = aH[1][mm][jj] + bhh[HH + jy];
            float in_ = aI[2][mm][jj] + bih[2 * HH + jy];
            float hn = aH[2][mm][jj] + bhh[2 * HH + jy];
            float r = 1.f / (1.f + __expf(-(ir + hr)));
            float z = 1.f / (1.f + __expf(-(iz + hz)));
            float t = in_ + r * hn;
            t = fminf(fmaxf(t, -10.f), 10.f);
            float ex = __expf(-2.f * t);
            float n = (1.f - ex) / (1.f + ex);
            float ho = hold[(size_t)row * SP + jy];
            hnew[(size_t)row * SP + jy] = (1.f - z) * n + z * ho;
        }
    }
}

// ---------- segment sum (graph_ids sorted) ----------
__global__ void k_seg(const float* __restrict__ h, const int* __restrict__ gid, float* __restrict__ g) {
    int f = threadIdx.x;
    if (f >= HH) return;
    int i0 = blockIdx.x * 512;
    int i1 = i0 + 512; if (i1 > NN) i1 = NN;
    float acc = 0.f;
    int cg = gid[i0];
    for (int i = i0; i < i1; i++) {
        int gg = gid[i];
        if (gg != cg) { atomicAdd(&g[cg * HH + f], acc); acc = 0.f; cg = gg; }
        acc += h[(size_t)i * SP + f];
    }
    atomicAdd(&g[cg * HH + f], acc);
}

// ---------- tiny readout MLP ----------
__global__ void k_mlp(const float* __restrict__ g, const float* __restrict__ pt,
                      const float* __restrict__ fc1p, const float* __restrict__ fc1b,
                      const float* __restrict__ fc2W, const float* __restrict__ fc2b,
                      const float* __restrict__ fcLW, const float* __restrict__ fcLb,
                      float* __restrict__ out) {
    __shared__ float X[GG][SP];
    __shared__ float Y[GG][80];
    __shared__ float Z[GG][80];
    int t = threadIdx.x;
    for (int idx = t; idx < GG * SP; idx += 256) {
        int gi = idx / SP, c = idx - gi * SP;
        float v;
        if (c < HH) {
            float vg = g[gi * HH + c];
            float lg = logf(vg);
            if (lg != lg) lg = 0.f;       // NaN (neg input) -> 0 ; -inf stays, relu kills it
            v = fmaxf(lg, 0.f);
        } else if (c == HH) v = pt[gi];
        else v = 0.f;
        X[gi][c] = v;
    }
    __syncthreads();
    for (int idx = t; idx < GG * 80; idx += 256) {
        int gi = idx / 80, o = idx - gi * 80;
        float acc = fc1b[o];
        for (int k = 0; k < HH + 1; k++) acc = fmaf(X[gi][k], fc1p[o * SP + k], acc);
        Y[gi][o] = acc > 0.f ? acc : 0.01f * acc;
    }
    __syncthreads();
    for (int idx = t; idx < GG * 80; idx += 256) {
        int gi = idx / 80, o = idx - gi * 80;
        float acc = fc2b[o];
        for (int k = 0; k < 80; k++) acc = fmaf(Y[gi][k], fc2W[o * 80 + k], acc);
        Z[gi][o] = acc > 0.f ? acc : 0.01f * acc;
    }
    __syncthreads();
    for (int idx = t; idx < GG * 10; idx += 256) {
        int gi = idx / 10, o = idx - gi * 10;
        float acc = fcLb[o];
        for (int k = 0; k < 80; k++) acc = fmaf(Z[gi][k], fcLW[o * 80 + k], acc);
        out[idx] = acc;
    }
}

extern "C" void kernel_launch(void* const* d_in, const int* in_sizes, int n_in,
                              void* d_out, int out_size, void* d_ws, size_t ws_size,
                              hipStream_t stream) {
    const float* nodes = (const float*)d_in[0];
    const float* pt    = (const float*)d_in[1];
    const float* W1s[2] = {(const float*)d_in[2], (const float*)d_in[6]};
    const float* b1s[2] = {(const float*)d_in[3], (const float*)d_in[7]};
    const float* W2s[2] = {(const float*)d_in[4], (const float*)d_in[8]};
    const float* b2s[2] = {(const float*)d_in[5], (const float*)d_in[9]};
    const float* Wih = (const float*)d_in[10];  const float* bih = (const float*)d_in[11];
    const float* Whh = (const float*)d_in[12];  const float* bhh = (const float*)d_in[13];
    const float* fc1W = (const float*)d_in[14]; const float* fc1b = (const float*)d_in[15];
    const float* fc2W = (const float*)d_in[16]; const float* fc2b = (const float*)d_in[17];
    const float* fcLW = (const float*)d_in[18]; const float* fcLb = (const float*)d_in[19];
    const int* edges[2] = {(const int*)d_in[20], (const int*)d_in[21]};
    const int* gid = (const int*)d_in[22];
    float* out = (float*)d_out;

    // workspace layout
    float* base = (float*)d_ws;
    float* hA  = base;
    float* hB  = hA + (size_t)NN * SP;
    float* inc = hB + (size_t)NN * SP;
    float* W1p0 = inc + (size_t)NN * SP;
    float* W2p0 = W1p0 + 192 * SP;
    float* W1p1 = W2p0 + 192 * SP;
    float* W2p1 = W1p1 + 192 * SP;
    float* Wihp = W2p1 + 192 * SP;
    float* Whhp = Wihp + 512 * SP;
    float* fc1p = Whhp + 512 * SP;
    float* gbuf = fc1p + 80 * SP;
    int* ip   = (int*)(gbuf + GG * HH);
    int* off0 = ip;
    int* off1 = off0 + NN + 1;
    int* cur  = off1 + NN + 1;
    int* hist = cur + NN;
    int* csr0 = hist + NN;
    int* csr1 = csr0 + EE;
    const float* W1p[2] = {W1p0, W1p1};
    const float* W2p[2] = {W2p0, W2p1};
    int* offs[2] = {off0, off1};
    int* csrs[2] = {csr0, csr1};

    // zero padded-weight region + g (contiguous)
    size_t wz = (size_t)(4 * 192 * SP + 2 * 512 * SP + 80 * SP + GG * HH) * sizeof(float);
    hipMemsetAsync(W1p0, 0, wz, stream);

    // pad weights
    k_pad<<<(150 * 150 + 255) / 256, 256, 0, stream>>>(W1s[0], W1p0, 150, 150);
    k_pad<<<(150 * 150 + 255) / 256, 256, 0, stream>>>(W2s[0], W2p0, 150, 150);
    k_pad<<<(150 * 150 + 255) / 256, 256, 0, stream>>>(W1s[1], W1p1, 150, 150);
    k_pad<<<(150 * 150 + 255) / 256, 256, 0, stream>>>(W2s[1], W2p1, 150, 150);
    k_pad<<<(450 * 150 + 255) / 256, 256, 0, stream>>>(Wih, Wihp, 450, 150);
    k_pad<<<(450 * 150 + 255) / 256, 256, 0, stream>>>(Whh, Whhp, 450, 150);
    k_pad<<<(80 * 151 + 255) / 256, 256, 0, stream>>>(fc1W, fc1p, 80, 151);

    // h init
    k_init<<<(NN * SP + 255) / 256, 256, 0, stream>>>(nodes, hA);

    // CSR build (once per call; reused for all passes)
    for (int s = 0; s < 2; s++) {
        hipMemsetAsync(hist, 0, NN * sizeof(int), stream);
        k_hist<<<(EE + 255) / 256, 256, 0, stream>>>(edges[s], hist);
        k_scan<<<1, 1024, 0, stream>>>(hist, offs[s], cur);
        k_fill<<<(EE + 255) / 256, 256, 0, stream>>>(edges[s], cur, csrs[s]);
    }

    // message passes
    float* hc = hA; float* hn = hB;
    dim3 gruGrid((NN + 63) / 64, 3);
    for (int p = 0; p < NPASS; p++) {
        for (int s = 0; s < 2; s++) {
            k_msg<<<(NN + 63) / 64, 256, 0, stream>>>(hc, W1p[s], b1s[s], W2p[s], b2s[s], hn);
            k_gather<<<(NN + 3) / 4, 256, 0, stream>>>(hn, offs[s], csrs[s], inc, s);
        }
        k_gru<<<gruGrid, 256, 0, stream>>>(inc, hc, Wihp, bih, Whhp, bhh, hn);
        float* t = hc; hc = hn; hn = t;
    }

    // readout
    k_seg<<<(NN + 511) / 512, 192, 0, stream>>>(hc, gid, gbuf);
    k_mlp<<<1, 256, 0, stream>>>(gbuf, pt, fc1p, fc1b, fc2W, fc2b, fcLW, fcLb, out);
}

// Round 3
// 3569.510 us; speedup vs baseline: 4.3813x; 4.3813x over previous
//
#include <hip/hip_runtime.h>

typedef unsigned short u16;
typedef unsigned int u32;
typedef __attribute__((ext_vector_type(8))) short s8v;      // 8 bf16
typedef __attribute__((ext_vector_type(8))) _Float16 h8v;   // 8 fp16
typedef __attribute__((ext_vector_type(4))) float f4v;      // C/D frag

#define NN 100000
#define MROW 100096
#define EE 500000
#define GG 16
#define HPIT 304      // h row pitch (u16): [hi 152 | lo 152]
#define UPIT 152      // u/U row pitch (u16): fp16 single
#define WPIT 320      // weight row pitch (u16): [hi 160 | lo 160]

__device__ __forceinline__ u16 f2bf(float x){ u32 u=__float_as_uint(x); return (u16)((u + 0x7fffu + ((u>>16)&1u))>>16); }
__device__ __forceinline__ float bf2f(u16 h){ return __uint_as_float(((u32)h)<<16); }
__device__ __forceinline__ u16 f2h(float x){ union{u16 u;_Float16 f;}c; c.f=(_Float16)x; return c.u; }
__device__ __forceinline__ float h2f(u16 b){ union{u16 u;_Float16 f;}c; c.u=b; return (float)c.f; }

#define GLOAD_LDS(gp, lp) \
    __builtin_amdgcn_global_load_lds((const __attribute__((address_space(1))) void*)(gp), \
                                     (__attribute__((address_space(3))) void*)(lp), 16, 0, 0)

// ---------------- MFMA helpers ----------------
template<int CS, bool ISBF>
__device__ __forceinline__ void mfma_block(const u16* lWt, int wn,int lr,int quad,int ks,
                                           f4v (&acc)[4][2], const s8v (&af)[4]) {
    constexpr int SPR = CS/8;
    s8v wf[2];
#pragma unroll
    for (int ni=0;ni<2;ni++){
        int row = wn*32 + ni*16 + lr;
        int ph = (ks*4 + quad) ^ (row & (SPR-1));
        wf[ni] = *(const s8v*)(lWt + row*CS + ph*8);
    }
#pragma unroll
    for (int mi=0;mi<4;mi++)
#pragma unroll
        for (int ni=0;ni<2;ni++){
            if constexpr (ISBF)
                acc[mi][ni] = __builtin_amdgcn_mfma_f32_16x16x32_bf16(af[mi], wf[ni], acc[mi][ni],0,0,0);
            else
                acc[mi][ni] = __builtin_amdgcn_mfma_f32_16x16x32_f16(*(const h8v*)&af[mi], *(const h8v*)&wf[ni], acc[mi][ni],0,0,0);
        }
}

// one stage-round: stage A 128xCS + NW W-tiles 64xCS, then MFMA into up to 3 acc sets
template<int CS, bool ISBF, int NW>
__device__ __forceinline__ void round_g(const u16* A, int ap, int aoff,
    const u16* W0, const u16* W1, const u16* W2, int woff,
    u16* lA, u16* lW, int m0, int n0, int tid, int wm,int wn,int lr,int quad,
    f4v (&acc0)[4][2], f4v (&acc1)[4][2], f4v (&acc2)[4][2])
{
    constexpr int SPR = CS/8;
    constexpr int LSH = (CS==64)?3:2;
    __syncthreads();                       // prev round's LDS reads done
    for (int s = tid; s < 128*SPR; s += 256){
        int row = s>>LSH, lq = s & (SPR-1);
        int q = lq ^ (row & (SPR-1));
        GLOAD_LDS(A + (size_t)(m0+row)*ap + aoff + q*8, lA + s*8);
    }
    for (int s = tid; s < NW*64*SPR; s += 256){
        int wsel = s/(64*SPR), rem = s - wsel*(64*SPR);
        int row = rem>>LSH, lq = rem & (SPR-1);
        int q = lq ^ (row & (SPR-1));
        const u16* W = (wsel==0)?W0:((wsel==1)?W1:W2);
        GLOAD_LDS(W + (size_t)(n0+row)*WPIT + woff + q*8, lW + s*8);
    }
    __syncthreads();                       // compiler drains vmcnt(0) here
#pragma unroll
    for (int ks=0; ks<CS/32; ks++){
        s8v af[4];
#pragma unroll
        for (int mi=0;mi<4;mi++){
            int row = wm*64 + mi*16 + lr;
            int ph = (ks*4 + quad) ^ (row & (SPR-1));
            af[mi] = *(const s8v*)(lA + row*CS + ph*8);
        }
        mfma_block<CS,ISBF>(lW + 0*64*CS, wn,lr,quad,ks, acc0, af);
        if (NW>1) mfma_block<CS,ISBF>(lW + 1*64*CS, wn,lr,quad,ks, acc1, af);
        if (NW>2) mfma_block<CS,ISBF>(lW + 2*64*CS, wn,lr,quad,ks, acc2, af);
    }
}

// ---------------- edge-MLP layer 1: u = lrelu(h @ W1^T + b1) -> fp16 ----------------
__global__ __launch_bounds__(256) void k_ugemm(const u16* __restrict__ H, const u16* __restrict__ W1b,
                                               const float* __restrict__ b1t, u16* __restrict__ Yu){
    __shared__ u16 lA[128*64];
    __shared__ u16 lW[64*64];
    int tid=threadIdx.x, wave=tid>>6, lane=tid&63, lr=lane&15, quad=lane>>4;
    int wm=wave>>1, wn=wave&1;
    int m0=blockIdx.x*128, n0=blockIdx.y*64;
    f4v acc[4][2] = {};
    const int apo[3]={0,152,0}, wpo[3]={0,0,160};   // (Ahi,Whi) (Alo,Whi) (Ahi,Wlo)
#pragma unroll
    for (int cb=0; cb<3; cb++){
        round_g<64,true,1>(H,HPIT,apo[cb]+0,  W1b,W1b,W1b,wpo[cb]+0,  lA,lW,m0,n0,tid,wm,wn,lr,quad, acc,acc,acc);
        round_g<64,true,1>(H,HPIT,apo[cb]+64, W1b,W1b,W1b,wpo[cb]+64, lA,lW,m0,n0,tid,wm,wn,lr,quad, acc,acc,acc);
        round_g<32,true,1>(H,HPIT,apo[cb]+128,W1b,W1b,W1b,wpo[cb]+128,lA,lW,m0,n0,tid,wm,wn,lr,quad, acc,acc,acc);
    }
#pragma unroll
    for (int ni=0;ni<2;ni++){
        int c = n0 + wn*32 + ni*16 + lr;
        if (c >= 152) continue;
        float bb = b1t[c];
#pragma unroll
        for (int mi=0;mi<4;mi++)
#pragma unroll
            for (int reg=0;reg<4;reg++){
                int r = m0 + wm*64 + mi*16 + quad*4 + reg;
                if (r >= NN) continue;
                float v = acc[mi][ni][reg] + bb;
                v = v>0.f ? v : 0.01f*v;
                if (c >= 150) v = 0.f;
                Yu[(size_t)r*UPIT + c] = f2h(v);
            }
    }
}

// ---------------- fused GRU mega-kernel ----------------
__global__ __launch_bounds__(256) void k_mega(const u16* __restrict__ H,
    const u16* __restrict__ U0, const u16* __restrict__ U1,
    const u16* __restrict__ Cr0,const u16* __restrict__ Cz0,const u16* __restrict__ Cn0,
    const u16* __restrict__ Cr1,const u16* __restrict__ Cz1,const u16* __restrict__ Cn1,
    const u16* __restrict__ Wr,const u16* __restrict__ Wz,const u16* __restrict__ Un,
    const float* __restrict__ tb,
    const int* __restrict__ off0, const int* __restrict__ off1,
    u16* __restrict__ Hn)
{
    __shared__ u16 lA[128*64];
    __shared__ u16 lW[3*64*64];
    int tid=threadIdx.x, wave=tid>>6, lane=tid&63, lr=lane&15, quad=lane>>4;
    int wm=wave>>1, wn=wave&1;
    int m0=blockIdx.x*128, n0=blockIdx.y*64;
    f4v aR[4][2]={}, aZ[4][2]={}, aI[4][2]={}, aH[4][2]={};
    // u-side (fp16): gates r,z,in from U0,U1 with composite weights (2 planes each)
    for (int s=0;s<2;s++){
        const u16* A  = s ? U1 : U0;
        const u16* Cr = s ? Cr1 : Cr0;
        const u16* Cz = s ? Cz1 : Cz0;
        const u16* Cn = s ? Cn1 : Cn0;
#pragma unroll
        for (int pl=0;pl<2;pl++){
            int wo = pl*160;
            round_g<64,false,3>(A,UPIT,0,   Cr,Cz,Cn,wo+0,  lA,lW,m0,n0,tid,wm,wn,lr,quad, aR,aZ,aI);
            round_g<64,false,3>(A,UPIT,64,  Cr,Cz,Cn,wo+64, lA,lW,m0,n0,tid,wm,wn,lr,quad, aR,aZ,aI);
            round_g<32,false,3>(A,UPIT,128, Cr,Cz,Cn,wo+128,lA,lW,m0,n0,tid,wm,wn,lr,quad, aR,aZ,aI);
        }
    }
    // h-side (bf16 split): gates r,z,hn
    const int apo[3]={0,152,0}, wpo[3]={0,0,160};
#pragma unroll
    for (int cb=0;cb<3;cb++){
        round_g<64,true,3>(H,HPIT,apo[cb]+0,  Wr,Wz,Un,wpo[cb]+0,  lA,lW,m0,n0,tid,wm,wn,lr,quad, aR,aZ,aH);
        round_g<64,true,3>(H,HPIT,apo[cb]+64, Wr,Wz,Un,wpo[cb]+64, lA,lW,m0,n0,tid,wm,wn,lr,quad, aR,aZ,aH);
        round_g<32,true,3>(H,HPIT,apo[cb]+128,Wr,Wz,Un,wpo[cb]+128,lA,lW,m0,n0,tid,wm,wn,lr,quad, aR,aZ,aH);
    }
    // epilogue: full GRU cell
#pragma unroll
    for (int ni=0;ni<2;ni++){
        int c = n0 + wn*32 + ni*16 + lr;
        if (c >= 152) continue;
        float bR=tb[c], bZ=tb[160+c], bI=tb[320+c], bHn=tb[480+c];
        float vr0=tb[640+c], vr1=tb[800+c], vz0=tb[960+c], vz1=tb[1120+c], vn0=tb[1280+c], vn1=tb[1440+c];
#pragma unroll
        for (int mi=0;mi<4;mi++)
#pragma unroll
            for (int reg=0;reg<4;reg++){
                int r = m0 + wm*64 + mi*16 + quad*4 + reg;
                if (r >= NN) continue;
                float d0 = (float)(off0[r+1]-off0[r]);
                float d1 = (float)(off1[r+1]-off1[r]);
                float pr = aR[mi][ni][reg] + bR + d0*vr0 + d1*vr1;
                float pz = aZ[mi][ni][reg] + bZ + d0*vz0 + d1*vz1;
                float pi = aI[mi][ni][reg] + bI + d0*vn0 + d1*vn1;
                float ph_= aH[mi][ni][reg] + bHn;
                float rg = 1.f/(1.f+expf(-pr));
                float zg = 1.f/(1.f+expf(-pz));
                float n  = tanhf(pi + rg*ph_);
                float hold = bf2f(H[(size_t)r*HPIT + c]) + bf2f(H[(size_t)r*HPIT + 152 + c]);
                float o = (1.f-zg)*n + zg*hold;
                if (c >= 150) o = 0.f;
                u16 hi = f2bf(o);
                Hn[(size_t)r*HPIT + c] = hi;
                Hn[(size_t)r*HPIT + 152 + c] = f2bf(o - bf2f(hi));
            }
    }
}

// ---------------- prep kernels ----------------
__global__ void k_splitW(const float* __restrict__ src, int rowoff, u16* __restrict__ dst){
    int idx = blockIdx.x*256 + threadIdx.x;     // 192*160
    if (idx >= 192*160) return;
    int r = idx/160, c = idx - r*160;
    float x = (r<150 && c<150) ? src[(size_t)(rowoff+r)*150 + c] : 0.f;
    u16 hi = f2bf(x);
    dst[(size_t)r*WPIT + c] = hi;
    dst[(size_t)r*WPIT + 160 + c] = f2bf(x - bf2f(hi));
}

__global__ void k_comp(const float* __restrict__ Wih, const float* __restrict__ W2_0,
                       const float* __restrict__ W2_1, u16* __restrict__ Cb){
    int idx = blockIdx.x*256 + threadIdx.x;     // 6*192*160
    if (idx >= 6*192*160) return;
    int mat = idx/(192*160), rem = idx - mat*(192*160);
    int o = rem/160, c = rem - o*160;
    int g = mat>>1, s = mat&1;
    float v = 0.f;
    if (o<150 && c<150){
        const float* W2 = s ? W2_1 : W2_0;
        for (int j=0;j<150;j++) v += Wih[(size_t)(g*150+o)*150 + j] * W2[(size_t)j*150 + c];
    }
    u16* D = Cb + (size_t)mat*192*WPIT;
    union{u16 u;_Float16 f;} h1,h2;
    h1.f = (_Float16)v;
    h2.f = (_Float16)(v - (float)h1.f);
    D[(size_t)o*WPIT + c] = h1.u;
    D[(size_t)o*WPIT + 160 + c] = h2.u;
}

__global__ void k_tabs(const float* bih,const float* bhh,const float* Wih,
                       const float* b2_0,const float* b2_1,
                       const float* b1_0,const float* b1_1,
                       float* tb, float* b1t0, float* b1t1){
    int idx = blockIdx.x*256 + threadIdx.x;     // 12*160
    if (idx >= 12*160) return;
    int t = idx/160, c = idx - t*160;
    float v = 0.f;
    if (c < 150){
        if (t==0) v = bih[c]+bhh[c];
        else if (t==1) v = bih[150+c]+bhh[150+c];
        else if (t==2) v = bih[300+c];
        else if (t==3) v = bhh[300+c];
        else if (t<10){
            int g=(t-4)>>1, s=(t-4)&1;
            const float* b2 = s ? b2_1 : b2_0;
            float a = 0.f;
            for (int j=0;j<150;j++) a += Wih[(size_t)(g*150+c)*150 + j]*b2[j];
            v = a;
        }
        else if (t==10) v = b1_0[c];
        else v = b1_1[c];
    }
    if (t<10) tb[t*160+c]=v;
    else if (t==10) b1t0[c]=v;
    else b1t1[c]=v;
}

__global__ void k_padfc1(const float* __restrict__ s, float* __restrict__ d){
    int idx = blockIdx.x*256 + threadIdx.x;     // 80*160
    if (idx >= 80*160) return;
    int r = idx/160, c = idx - r*160;
    d[idx] = (c<151) ? s[r*151 + c] : 0.f;
}

__global__ void k_inith(const float* __restrict__ nodes, u16* __restrict__ H){
    int idx = blockIdx.x*256 + threadIdx.x;     // NN*152
    if (idx >= NN*152) return;
    int m = idx/152, c = idx - m*152;
    float x = (c<150) ? nodes[(size_t)m*150 + c] : 0.f;
    u16 hi = f2bf(x);
    H[(size_t)m*HPIT + c] = hi;
    H[(size_t)m*HPIT + 152 + c] = f2bf(x - bf2f(hi));
}

// ---------------- CSR build (R1-proven) ----------------
__global__ void k_hist(const int* __restrict__ edges, int* __restrict__ cnt){
    int e = blockIdx.x*256 + threadIdx.x;
    if (e >= EE) return;
    atomicAdd(&cnt[edges[2*e]], 1);
}

__global__ __launch_bounds__(1024) void k_scan(const int* __restrict__ cnt,
                                               int* __restrict__ off, int* __restrict__ cur){
    __shared__ int sd[1024];
    __shared__ int s_run;
    int t = threadIdx.x;
    if (t==0) s_run = 0;
    __syncthreads();
    for (int base=0; base<NN; base+=8192){
        int i0 = base + t*8;
        int v[8]; int s = 0;
#pragma unroll
        for (int u=0; u<8; u++){ int i=i0+u; v[u]=(i<NN)?cnt[i]:0; s+=v[u]; }
        sd[t]=s;
        __syncthreads();
        int runbase = s_run;
        for (int ofs=1; ofs<1024; ofs<<=1){
            int y=0;
            if (t>=ofs) y=sd[t-ofs];
            __syncthreads();
            if (t>=ofs) sd[t]+=y;
            __syncthreads();
        }
        int excl = runbase + sd[t] - s;
#pragma unroll
        for (int u=0; u<8; u++){
            int i=i0+u;
            if (i<NN){ off[i]=excl; cur[i]=excl; excl+=v[u]; }
        }
        __syncthreads();
        if (t==1023) s_run = runbase + sd[1023];
        __syncthreads();
    }
    if (t==0) off[NN] = s_run;
}

__global__ void k_fill(const int* __restrict__ edges, int* __restrict__ cur, int* __restrict__ csr){
    int e = blockIdx.x*256 + threadIdx.x;
    if (e >= EE) return;
    int dst = edges[2*e], src = edges[2*e+1];
    int pos = atomicAdd(&cur[dst], 1);
    csr[pos] = src;
}

// ---------------- gather: U[d] = sum_{e in CSR[d]} u[src[e]] ----------------
__global__ void k_gath(const u16* __restrict__ u, const int* __restrict__ off,
                       const int* __restrict__ csr, u16* __restrict__ U){
    int d = blockIdx.x*4 + (threadIdx.x>>6);
    if (d >= NN) return;
    int lane = threadIdx.x & 63;
    int e0 = off[d], e1 = off[d+1];
    float a0=0.f, a1=0.f, a2=0.f;
    for (int e=e0; e<e1; e++){
        const u16* r = u + (size_t)csr[e]*UPIT;
        a0 += h2f(r[lane]);
        a1 += h2f(r[lane+64]);
        if (lane < 24) a2 += h2f(r[lane+128]);
    }
    U[(size_t)d*UPIT + lane]      = f2h(a0);
    U[(size_t)d*UPIT + lane + 64] = f2h(a1);
    if (lane < 24) U[(size_t)d*UPIT + lane + 128] = f2h(a2);
}

// ---------------- segment sum + readout ----------------
__global__ void k_seg(const u16* __restrict__ H, const int* __restrict__ gid, float* __restrict__ g){
    int f = threadIdx.x;
    if (f >= 150) return;
    int i0 = blockIdx.x*512;
    int i1 = i0 + 512; if (i1 > NN) i1 = NN;
    float acc = 0.f;
    int cg = gid[i0];
    for (int i=i0; i<i1; i++){
        int gg = gid[i];
        if (gg != cg){ atomicAdd(&g[cg*150+f], acc); acc=0.f; cg=gg; }
        acc += bf2f(H[(size_t)i*HPIT + f]) + bf2f(H[(size_t)i*HPIT + 152 + f]);
    }
    atomicAdd(&g[cg*150+f], acc);
}

__global__ void k_mlp(const float* __restrict__ g, const float* __restrict__ pt,
                      const float* __restrict__ fc1p, const float* __restrict__ fc1b,
                      const float* __restrict__ fc2W, const float* __restrict__ fc2b,
                      const float* __restrict__ fcLW, const float* __restrict__ fcLb,
                      float* __restrict__ out){
    __shared__ float X[GG][152];
    __shared__ float Y[GG][80];
    __shared__ float Z[GG][80];
    int t = threadIdx.x;
    for (int idx=t; idx<GG*152; idx+=256){
        int gi=idx/152, c=idx-gi*152;
        float v = 0.f;
        if (c < 150){
            float lg = logf(g[gi*150+c]);
            if (lg != lg) lg = 0.f;
            v = fmaxf(lg, 0.f);
        } else if (c == 150) v = pt[gi];
        X[gi][c] = v;
    }
    __syncthreads();
    for (int idx=t; idx<GG*80; idx+=256){
        int gi=idx/80, o=idx-gi*80;
        float acc = fc1b[o];
        for (int k=0;k<151;k++) acc = fmaf(X[gi][k], fc1p[o*160+k], acc);
        Y[gi][o] = acc>0.f ? acc : 0.01f*acc;
    }
    __syncthreads();
    for (int idx=t; idx<GG*80; idx+=256){
        int gi=idx/80, o=idx-gi*80;
        float acc = fc2b[o];
        for (int k=0;k<80;k++) acc = fmaf(Y[gi][k], fc2W[o*80+k], acc);
        Z[gi][o] = acc>0.f ? acc : 0.01f*acc;
    }
    __syncthreads();
    for (int idx=t; idx<GG*10; idx+=256){
        int gi=idx/10, o=idx-gi*10;
        float acc = fcLb[o];
        for (int k=0;k<80;k++) acc = fmaf(Z[gi][k], fcLW[o*80+k], acc);
        out[idx] = acc;
    }
}

// ---------------- host ----------------
extern "C" void kernel_launch(void* const* d_in, const int* in_sizes, int n_in,
                              void* d_out, int out_size, void* d_ws, size_t ws_size,
                              hipStream_t stream) {
    const float* nodes = (const float*)d_in[0];
    const float* pt    = (const float*)d_in[1];
    const float* W1_0 = (const float*)d_in[2];  const float* b1_0 = (const float*)d_in[3];
    const float* W2_0 = (const float*)d_in[4];  const float* b2_0 = (const float*)d_in[5];
    const float* W1_1 = (const float*)d_in[6];  const float* b1_1 = (const float*)d_in[7];
    const float* W2_1 = (const float*)d_in[8];  const float* b2_1 = (const float*)d_in[9];
    const float* Wih = (const float*)d_in[10];  const float* bih = (const float*)d_in[11];
    const float* Whh = (const float*)d_in[12];  const float* bhh = (const float*)d_in[13];
    const float* fc1W = (const float*)d_in[14]; const float* fc1b = (const float*)d_in[15];
    const float* fc2W = (const float*)d_in[16]; const float* fc2b = (const float*)d_in[17];
    const float* fcLW = (const float*)d_in[18]; const float* fcLb = (const float*)d_in[19];
    const int* edges[2] = {(const int*)d_in[20], (const int*)d_in[21]};
    const int* gid = (const int*)d_in[22];
    float* out = (float*)d_out;

    char* p = (char*)d_ws;
    auto alloc = [&](size_t bytes){ char* r = p; p += (bytes + 255) & ~(size_t)255; return r; };
    // big buffers (total ~177 MB; whole layout ~184 MB, within the R1-proven budget)
    u16* XA = (u16*)alloc((size_t)MROW*HPIT*2);
    u16* XB = (u16*)alloc((size_t)MROW*HPIT*2);
    u16* U0 = (u16*)alloc((size_t)MROW*UPIT*2);
    u16* U1 = (u16*)alloc((size_t)MROW*UPIT*2);
    // weights
    u16* W1b0 = (u16*)alloc(192*WPIT*2);
    u16* W1b1 = (u16*)alloc(192*WPIT*2);
    u16* Wr = (u16*)alloc(192*WPIT*2);
    u16* Wz = (u16*)alloc(192*WPIT*2);
    u16* Un = (u16*)alloc(192*WPIT*2);
    u16* Cb = (u16*)alloc((size_t)6*192*WPIT*2);
    float* tb   = (float*)alloc(10*160*4);
    float* b1t0 = (float*)alloc(160*4);
    float* b1t1 = (float*)alloc(160*4);
    float* fc1p = (float*)alloc(80*160*4);
    float* gbuf = (float*)alloc(GG*150*4);
    int* off0 = (int*)alloc((NN+1)*4);
    int* off1 = (int*)alloc((NN+1)*4);
    int* cur  = (int*)alloc(NN*4);
    int* hist = (int*)alloc(NN*4);
    int* csr0 = (int*)alloc((size_t)EE*4);
    int* csr1 = (int*)alloc((size_t)EE*4);
    (void)alloc(4096);   // tail pad for harmless last-row K-chunk overrun reads
    int* offs[2] = {off0, off1};
    int* csrs[2] = {csr0, csr1};

    // ---- prep ----
    k_splitW<<<120, 256, 0, stream>>>(W1_0, 0, W1b0);
    k_splitW<<<120, 256, 0, stream>>>(W1_1, 0, W1b1);
    k_splitW<<<120, 256, 0, stream>>>(Whh, 0,   Wr);
    k_splitW<<<120, 256, 0, stream>>>(Whh, 150, Wz);
    k_splitW<<<120, 256, 0, stream>>>(Whh, 300, Un);
    k_comp<<<(6*192*160 + 255)/256, 256, 0, stream>>>(Wih, W2_0, W2_1, Cb);
    k_tabs<<<(12*160 + 255)/256, 256, 0, stream>>>(bih, bhh, Wih, b2_0, b2_1, b1_0, b1_1, tb, b1t0, b1t1);
    k_padfc1<<<50, 256, 0, stream>>>(fc1W, fc1p);
    k_inith<<<(NN*152 + 255)/256, 256, 0, stream>>>(nodes, XA);

    // ---- CSR ----
    for (int s=0; s<2; s++){
        hipMemsetAsync(hist, 0, NN*sizeof(int), stream);
        k_hist<<<(EE+255)/256, 256, 0, stream>>>(edges[s], hist);
        k_scan<<<1, 1024, 0, stream>>>(hist, offs[s], cur);
        k_fill<<<(EE+255)/256, 256, 0, stream>>>(edges[s], cur, csrs[s]);
    }

    // composite weight pointers: mat = gate*2 + set
    size_t wsz = (size_t)192*WPIT;
    const u16* Cr0 = Cb + 0*wsz; const u16* Cr1 = Cb + 1*wsz;
    const u16* Cz0 = Cb + 2*wsz; const u16* Cz1 = Cb + 3*wsz;
    const u16* Cn0 = Cb + 4*wsz; const u16* Cn1 = Cb + 5*wsz;

    // ---- message passes ----
    u16* Hc = XA; u16* Hx = XB;
    dim3 gT(MROW/128, 3);
    for (int ps=0; ps<4; ps++){
        u16* Yu = Hx;   // u scratch aliases h_next (first 30.4 MB); dead before mega writes Hx
        k_ugemm<<<gT, 256, 0, stream>>>(Hc, W1b0, b1t0, Yu);
        k_gath<<<(NN+3)/4, 256, 0, stream>>>(Yu, off0, csr0, U0);
        k_ugemm<<<gT, 256, 0, stream>>>(Hc, W1b1, b1t1, Yu);
        k_gath<<<(NN+3)/4, 256, 0, stream>>>(Yu, off1, csr1, U1);
        k_mega<<<gT, 256, 0, stream>>>(Hc, U0, U1, Cr0,Cz0,Cn0, Cr1,Cz1,Cn1,
                                       Wr, Wz, Un, tb, off0, off1, Hx);
        u16* t = Hc; Hc = Hx; Hx = t;
    }

    // ---- readout ----
    hipMemsetAsync(gbuf, 0, GG*150*sizeof(float), stream);
    k_seg<<<(NN+511)/512, 192, 0, stream>>>(Hc, gid, gbuf);
    k_mlp<<<1, 256, 0, stream>>>(gbuf, pt, fc1p, fc1b, fc2W, fc2b, fcLW, fcLb, out);
}

// Round 4
// 2680.633 us; speedup vs baseline: 5.8341x; 1.3316x over previous
//
#include <hip/hip_runtime.h>

typedef unsigned short u16;
typedef unsigned int u32;
typedef __attribute__((ext_vector_type(8))) short s8v;      // 8 bf16
typedef __attribute__((ext_vector_type(8))) _Float16 h8v;   // 8 fp16
typedef __attribute__((ext_vector_type(4))) float f4v;      // C/D frag

#define NN 100000
#define MROW 100096
#define EE 500000
#define GG 16
#define HPIT 304      // h row pitch (u16): [hi 152 | lo 152]
#define UPIT 152      // u/U row pitch (u16): fp16 single
#define WPIT 320      // weight row pitch (u16): [hi 160 | lo 160]

__device__ __forceinline__ u16 f2bf(float x){ u32 u=__float_as_uint(x); return (u16)((u + 0x7fffu + ((u>>16)&1u))>>16); }
__device__ __forceinline__ float bf2f(u16 h){ return __uint_as_float(((u32)h)<<16); }
__device__ __forceinline__ u16 f2h(float x){ union{u16 u;_Float16 f;}c; c.f=(_Float16)x; return c.u; }
__device__ __forceinline__ float h2f(u16 b){ union{u16 u;_Float16 f;}c; c.u=b; return (float)c.f; }

#define GLOAD_LDS(gp, lp) \
    __builtin_amdgcn_global_load_lds((const __attribute__((address_space(1))) void*)(gp), \
                                     (__attribute__((address_space(3))) void*)(lp), 16, 0, 0)

// ---------------- MFMA helpers ----------------
template<bool ISBF>
__device__ __forceinline__ void mfma4(const u16* wp, const s8v (&af)[4], f4v (&acc)[4]){
    s8v wf = *(const s8v*)wp;
#pragma unroll
    for (int mi=0;mi<4;mi++){
        if constexpr (ISBF)
            acc[mi] = __builtin_amdgcn_mfma_f32_16x16x32_bf16(af[mi], wf, acc[mi],0,0,0);
        else
            acc[mi] = __builtin_amdgcn_mfma_f32_16x16x32_f16(*(const h8v*)&af[mi], *(const h8v*)&wf, acc[mi],0,0,0);
    }
}

// one stage-round: 64M A-tile + NW 64-row W-tiles, wave wv owns output cols wv*16..+15
template<int CS, bool ISBF, int NW>
__device__ __forceinline__ void round64(const u16* A, int ap, int aoff,
    const u16* W0, const u16* W1, const u16* W2, int woff,
    u16* lA, u16* lW, int m0, int n0, int tid, int wv, int lr, int quad,
    f4v (&acc0)[4], f4v (&acc1)[4], f4v (&acc2)[4])
{
    constexpr int SPR = CS/8;
    constexpr int LSH = (CS==64)?3:2;
    __syncthreads();                       // prev round's LDS reads done
    for (int s = tid; s < 64*SPR; s += 256){
        int row = s>>LSH, lq = s & (SPR-1);
        int q = lq ^ (row & (SPR-1));
        GLOAD_LDS(A + (size_t)(m0+row)*ap + aoff + q*8, lA + s*8);
    }
    for (int s = tid; s < NW*64*SPR; s += 256){
        int wsel = s/(64*SPR), rem = s - wsel*(64*SPR);
        int row = rem>>LSH, lq = rem & (SPR-1);
        int q = lq ^ (row & (SPR-1));
        const u16* W = (wsel==0)?W0:((wsel==1)?W1:W2);
        GLOAD_LDS(W + (size_t)(n0+row)*WPIT + woff + q*8, lW + wsel*(64*CS) + rem*8);
    }
    __syncthreads();                       // compiler drains vmcnt(0) here
#pragma unroll
    for (int ks=0; ks<CS/32; ks++){
        s8v af[4];
#pragma unroll
        for (int mi=0;mi<4;mi++){
            int row = mi*16 + lr;
            int ph = (ks*4 + quad) ^ (row & (SPR-1));
            af[mi] = *(const s8v*)(lA + row*CS + ph*8);
        }
        int wrow = wv*16 + lr;
        int wph = (ks*4 + quad) ^ (wrow & (SPR-1));
        mfma4<ISBF>(lW + 0*64*CS + wrow*CS + wph*8, af, acc0);
        if (NW>1) mfma4<ISBF>(lW + 1*64*CS + wrow*CS + wph*8, af, acc1);
        if (NW>2) mfma4<ISBF>(lW + 2*64*CS + wrow*CS + wph*8, af, acc2);
    }
}

// ---------------- edge-MLP layer 1 (both edge sets): u_s = lrelu(h @ W1_s^T + b1_s) ----------------
__global__ __launch_bounds__(256,3) void k_ugemm2(const u16* __restrict__ H,
    const u16* __restrict__ W1b0, const u16* __restrict__ W1b1,
    const float* __restrict__ b1t0, const float* __restrict__ b1t1,
    u16* __restrict__ u0, u16* __restrict__ u1)
{
    __shared__ u16 lA[64*64];
    __shared__ u16 lW[2*64*64];
    int tid=threadIdx.x, wv=tid>>6, lane=tid&63, lr=lane&15, quad=lane>>4;
    int m0=blockIdx.x*64, n0=blockIdx.y*64;
    f4v a0[4]={}, a1[4]={};
    const int apo[3]={0,152,0}, wpo[3]={0,0,160};   // (Ahi,Whi) (Alo,Whi) (Ahi,Wlo)
#pragma unroll
    for (int cb=0; cb<3; cb++){
        round64<64,true,2>(H,HPIT,apo[cb]+0,  W1b0,W1b1,W1b1,wpo[cb]+0,  lA,lW,m0,n0,tid,wv,lr,quad, a0,a1,a1);
        round64<64,true,2>(H,HPIT,apo[cb]+64, W1b0,W1b1,W1b1,wpo[cb]+64, lA,lW,m0,n0,tid,wv,lr,quad, a0,a1,a1);
        round64<32,true,2>(H,HPIT,apo[cb]+128,W1b0,W1b1,W1b1,wpo[cb]+128,lA,lW,m0,n0,tid,wv,lr,quad, a0,a1,a1);
    }
    int c = n0 + wv*16 + lr;
    if (c < 152){
        float bb0 = b1t0[c], bb1 = b1t1[c];
#pragma unroll
        for (int mi=0;mi<4;mi++)
#pragma unroll
            for (int reg=0;reg<4;reg++){
                int r = m0 + mi*16 + quad*4 + reg;
                if (r >= NN) continue;
                float v0 = a0[mi][reg] + bb0;
                v0 = v0>0.f ? v0 : 0.01f*v0;
                float v1 = a1[mi][reg] + bb1;
                v1 = v1>0.f ? v1 : 0.01f*v1;
                if (c >= 150){ v0 = 0.f; v1 = 0.f; }
                u0[(size_t)r*UPIT + c] = f2h(v0);
                u1[(size_t)r*UPIT + c] = f2h(v1);
            }
    }
}

// ---------------- fused GRU mega-kernel (64M x 64N blocks) ----------------
__global__ __launch_bounds__(256,3) void k_mega(const u16* __restrict__ H,
    const u16* __restrict__ U0, const u16* __restrict__ U1,
    const u16* __restrict__ Cr0,const u16* __restrict__ Cz0,const u16* __restrict__ Cn0,
    const u16* __restrict__ Cr1,const u16* __restrict__ Cz1,const u16* __restrict__ Cn1,
    const u16* __restrict__ Wr,const u16* __restrict__ Wz,const u16* __restrict__ Un,
    const float* __restrict__ tb,
    const int* __restrict__ off0, const int* __restrict__ off1,
    u16* __restrict__ Hn)
{
    __shared__ u16 lA[64*64];
    __shared__ u16 lW[3*64*64];
    int tid=threadIdx.x, wv=tid>>6, lane=tid&63, lr=lane&15, quad=lane>>4;
    int m0=blockIdx.x*64, n0=blockIdx.y*64;
    f4v aR[4]={}, aZ[4]={}, aI[4]={}, aH[4]={};
    // u-side (fp16): gates r,z,in from U0,U1 with composite weights (2 planes each)
    for (int s=0;s<2;s++){
        const u16* A  = s ? U1 : U0;
        const u16* Cr = s ? Cr1 : Cr0;
        const u16* Cz = s ? Cz1 : Cz0;
        const u16* Cn = s ? Cn1 : Cn0;
#pragma unroll
        for (int pl=0;pl<2;pl++){
            int wo = pl*160;
            round64<64,false,3>(A,UPIT,0,   Cr,Cz,Cn,wo+0,  lA,lW,m0,n0,tid,wv,lr,quad, aR,aZ,aI);
            round64<64,false,3>(A,UPIT,64,  Cr,Cz,Cn,wo+64, lA,lW,m0,n0,tid,wv,lr,quad, aR,aZ,aI);
            round64<32,false,3>(A,UPIT,128, Cr,Cz,Cn,wo+128,lA,lW,m0,n0,tid,wv,lr,quad, aR,aZ,aI);
        }
    }
    // h-side (bf16 split): gates r,z,hn
    const int apo[3]={0,152,0}, wpo[3]={0,0,160};
#pragma unroll
    for (int cb=0;cb<3;cb++){
        round64<64,true,3>(H,HPIT,apo[cb]+0,  Wr,Wz,Un,wpo[cb]+0,  lA,lW,m0,n0,tid,wv,lr,quad, aR,aZ,aH);
        round64<64,true,3>(H,HPIT,apo[cb]+64, Wr,Wz,Un,wpo[cb]+64, lA,lW,m0,n0,tid,wv,lr,quad, aR,aZ,aH);
        round64<32,true,3>(H,HPIT,apo[cb]+128,Wr,Wz,Un,wpo[cb]+128,lA,lW,m0,n0,tid,wv,lr,quad, aR,aZ,aH);
    }
    // epilogue: full GRU cell
    int c = n0 + wv*16 + lr;
    if (c < 152){
        float bR=tb[c], bZ=tb[160+c], bI=tb[320+c], bHn=tb[480+c];
        float vr0=tb[640+c], vr1=tb[800+c], vz0=tb[960+c], vz1=tb[1120+c], vn0=tb[1280+c], vn1=tb[1440+c];
#pragma unroll
        for (int mi=0;mi<4;mi++)
#pragma unroll
            for (int reg=0;reg<4;reg++){
                int r = m0 + mi*16 + quad*4 + reg;
                if (r >= NN) continue;
                float d0 = (float)(off0[r+1]-off0[r]);
                float d1 = (float)(off1[r+1]-off1[r]);
                float pr = aR[mi][reg] + bR + d0*vr0 + d1*vr1;
                float pz = aZ[mi][reg] + bZ + d0*vz0 + d1*vz1;
                float pi = aI[mi][reg] + bI + d0*vn0 + d1*vn1;
                float ph_= aH[mi][reg] + bHn;
                float rg = 1.f/(1.f+expf(-pr));
                float zg = 1.f/(1.f+expf(-pz));
                float n  = tanhf(pi + rg*ph_);
                float hold = bf2f(H[(size_t)r*HPIT + c]) + bf2f(H[(size_t)r*HPIT + 152 + c]);
                float o = (1.f-zg)*n + zg*hold;
                if (c >= 150) o = 0.f;
                u16 hi = f2bf(o);
                Hn[(size_t)r*HPIT + c] = hi;
                Hn[(size_t)r*HPIT + 152 + c] = f2bf(o - bf2f(hi));
            }
    }
}

// ---------------- prep kernels ----------------
__global__ void k_splitW(const float* __restrict__ src, int rowoff, u16* __restrict__ dst){
    int idx = blockIdx.x*256 + threadIdx.x;     // 192*160
    if (idx >= 192*160) return;
    int r = idx/160, c = idx - r*160;
    float x = (r<150 && c<150) ? src[(size_t)(rowoff+r)*150 + c] : 0.f;
    u16 hi = f2bf(x);
    dst[(size_t)r*WPIT + c] = hi;
    dst[(size_t)r*WPIT + 160 + c] = f2bf(x - bf2f(hi));
}

__global__ void k_comp(const float* __restrict__ Wih, const float* __restrict__ W2_0,
                       const float* __restrict__ W2_1, u16* __restrict__ Cb){
    int idx = blockIdx.x*256 + threadIdx.x;     // 6*192*160
    if (idx >= 6*192*160) return;
    int mat = idx/(192*160), rem = idx - mat*(192*160);
    int o = rem/160, c = rem - o*160;
    int g = mat>>1, s = mat&1;
    float v = 0.f;
    if (o<150 && c<150){
        const float* W2 = s ? W2_1 : W2_0;
        for (int j=0;j<150;j++) v += Wih[(size_t)(g*150+o)*150 + j] * W2[(size_t)j*150 + c];
    }
    u16* D = Cb + (size_t)mat*192*WPIT;
    union{u16 u;_Float16 f;} h1,h2;
    h1.f = (_Float16)v;
    h2.f = (_Float16)(v - (float)h1.f);
    D[(size_t)o*WPIT + c] = h1.u;
    D[(size_t)o*WPIT + 160 + c] = h2.u;
}

__global__ void k_tabs(const float* bih,const float* bhh,const float* Wih,
                       const float* b2_0,const float* b2_1,
                       const float* b1_0,const float* b1_1,
                       float* tb, float* b1t0, float* b1t1){
    int idx = blockIdx.x*256 + threadIdx.x;     // 12*160
    if (idx >= 12*160) return;
    int t = idx/160, c = idx - t*160;
    float v = 0.f;
    if (c < 150){
        if (t==0) v = bih[c]+bhh[c];
        else if (t==1) v = bih[150+c]+bhh[150+c];
        else if (t==2) v = bih[300+c];
        else if (t==3) v = bhh[300+c];
        else if (t<10){
            int g=(t-4)>>1, s=(t-4)&1;
            const float* b2 = s ? b2_1 : b2_0;
            float a = 0.f;
            for (int j=0;j<150;j++) a += Wih[(size_t)(g*150+c)*150 + j]*b2[j];
            v = a;
        }
        else if (t==10) v = b1_0[c];
        else v = b1_1[c];
    }
    if (t<10) tb[t*160+c]=v;
    else if (t==10) b1t0[c]=v;
    else b1t1[c]=v;
}

__global__ void k_padfc1(const float* __restrict__ s, float* __restrict__ d){
    int idx = blockIdx.x*256 + threadIdx.x;     // 80*160
    if (idx >= 80*160) return;
    int r = idx/160, c = idx - r*160;
    d[idx] = (c<151) ? s[r*151 + c] : 0.f;
}

__global__ void k_inith(const float* __restrict__ nodes, u16* __restrict__ H){
    int idx = blockIdx.x*256 + threadIdx.x;     // NN*152
    if (idx >= NN*152) return;
    int m = idx/152, c = idx - m*152;
    float x = (c<150) ? nodes[(size_t)m*150 + c] : 0.f;
    u16 hi = f2bf(x);
    H[(size_t)m*HPIT + c] = hi;
    H[(size_t)m*HPIT + 152 + c] = f2bf(x - bf2f(hi));
}

// ---------------- CSR build ----------------
__global__ void k_hist(const int* __restrict__ edges, int* __restrict__ cnt){
    int e = blockIdx.x*256 + threadIdx.x;
    if (e >= EE) return;
    atomicAdd(&cnt[edges[2*e]], 1);
}

__global__ __launch_bounds__(1024) void k_scan(const int* __restrict__ cnt,
                                               int* __restrict__ off, int* __restrict__ cur){
    __shared__ int sd[1024];
    __shared__ int s_run;
    int t = threadIdx.x;
    if (t==0) s_run = 0;
    __syncthreads();
    for (int base=0; base<NN; base+=8192){
        int i0 = base + t*8;
        int v[8]; int s = 0;
#pragma unroll
        for (int u=0; u<8; u++){ int i=i0+u; v[u]=(i<NN)?cnt[i]:0; s+=v[u]; }
        sd[t]=s;
        __syncthreads();
        int runbase = s_run;
        for (int ofs=1; ofs<1024; ofs<<=1){
            int y=0;
            if (t>=ofs) y=sd[t-ofs];
            __syncthreads();
            if (t>=ofs) sd[t]+=y;
            __syncthreads();
        }
        int excl = runbase + sd[t] - s;
#pragma unroll
        for (int u=0; u<8; u++){
            int i=i0+u;
            if (i<NN){ off[i]=excl; cur[i]=excl; excl+=v[u]; }
        }
        __syncthreads();
        if (t==1023) s_run = runbase + sd[1023];
        __syncthreads();
    }
    if (t==0) off[NN] = s_run;
}

__global__ void k_fill(const int* __restrict__ edges, int* __restrict__ cur, int* __restrict__ csr){
    int e = blockIdx.x*256 + threadIdx.x;
    if (e >= EE) return;
    int dst = edges[2*e], src = edges[2*e+1];
    int pos = atomicAdd(&cur[dst], 1);
    csr[pos] = src;
}

// ---------------- gather both sets: U_s[d] = sum_{e in CSR_s[d]} u_s[src[e]] ----------------
__global__ void k_gath2(const u16* __restrict__ u0, const u16* __restrict__ u1,
                        const int* __restrict__ off0, const int* __restrict__ csr0,
                        const int* __restrict__ off1, const int* __restrict__ csr1,
                        u16* __restrict__ U0, u16* __restrict__ U1){
    int d = blockIdx.x*4 + (threadIdx.x>>6);
    if (d >= NN) return;
    int lane = threadIdx.x & 63;
    const u16* u = blockIdx.y ? u1 : u0;
    const int* off = blockIdx.y ? off1 : off0;
    const int* csr = blockIdx.y ? csr1 : csr0;
    u16* U = blockIdx.y ? U1 : U0;
    int e0 = off[d], e1 = off[d+1];
    float a0=0.f, a1=0.f, a2=0.f;
    for (int e=e0; e<e1; e++){
        const u16* r = u + (size_t)csr[e]*UPIT;
        a0 += h2f(r[lane]);
        a1 += h2f(r[lane+64]);
        if (lane < 24) a2 += h2f(r[lane+128]);
    }
    U[(size_t)d*UPIT + lane]      = f2h(a0);
    U[(size_t)d*UPIT + lane + 64] = f2h(a1);
    if (lane < 24) U[(size_t)d*UPIT + lane + 128] = f2h(a2);
}

// ---------------- segment sum + readout ----------------
__global__ void k_seg(const u16* __restrict__ H, const int* __restrict__ gid, float* __restrict__ g){
    int f = threadIdx.x;
    if (f >= 150) return;
    int i0 = blockIdx.x*512;
    int i1 = i0 + 512; if (i1 > NN) i1 = NN;
    float acc = 0.f;
    int cg = gid[i0];
    for (int i=i0; i<i1; i++){
        int gg = gid[i];
        if (gg != cg){ atomicAdd(&g[cg*150+f], acc); acc=0.f; cg=gg; }
        acc += bf2f(H[(size_t)i*HPIT + f]) + bf2f(H[(size_t)i*HPIT + 152 + f]);
    }
    atomicAdd(&g[cg*150+f], acc);
}

__global__ void k_mlp(const float* __restrict__ g, const float* __restrict__ pt,
                      const float* __restrict__ fc1p, const float* __restrict__ fc1b,
                      const float* __restrict__ fc2W, const float* __restrict__ fc2b,
                      const float* __restrict__ fcLW, const float* __restrict__ fcLb,
                      float* __restrict__ out){
    __shared__ float X[GG][152];
    __shared__ float Y[GG][80];
    __shared__ float Z[GG][80];
    int t = threadIdx.x;
    for (int idx=t; idx<GG*152; idx+=256){
        int gi=idx/152, c=idx-gi*152;
        float v = 0.f;
        if (c < 150){
            float lg = logf(g[gi*150+c]);
            if (lg != lg) lg = 0.f;
            v = fmaxf(lg, 0.f);
        } else if (c == 150) v = pt[gi];
        X[gi][c] = v;
    }
    __syncthreads();
    for (int idx=t; idx<GG*80; idx+=256){
        int gi=idx/80, o=idx-gi*80;
        float acc = fc1b[o];
        for (int k=0;k<151;k++) acc = fmaf(X[gi][k], fc1p[o*160+k], acc);
        Y[gi][o] = acc>0.f ? acc : 0.01f*acc;
    }
    __syncthreads();
    for (int idx=t; idx<GG*80; idx+=256){
        int gi=idx/80, o=idx-gi*80;
        float acc = fc2b[o];
        for (int k=0;k<80;k++) acc = fmaf(Y[gi][k], fc2W[o*80+k], acc);
        Z[gi][o] = acc>0.f ? acc : 0.01f*acc;
    }
    __syncthreads();
    for (int idx=t; idx<GG*10; idx+=256){
        int gi=idx/10, o=idx-gi*10;
        float acc = fcLb[o];
        for (int k=0;k<80;k++) acc = fmaf(Z[gi][k], fcLW[o*80+k], acc);
        out[idx] = acc;
    }
}

// ---------------- host ----------------
extern "C" void kernel_launch(void* const* d_in, const int* in_sizes, int n_in,
                              void* d_out, int out_size, void* d_ws, size_t ws_size,
                              hipStream_t stream) {
    const float* nodes = (const float*)d_in[0];
    const float* pt    = (const float*)d_in[1];
    const float* W1_0 = (const float*)d_in[2];  const float* b1_0 = (const float*)d_in[3];
    const float* W2_0 = (const float*)d_in[4];  const float* b2_0 = (const float*)d_in[5];
    const float* W1_1 = (const float*)d_in[6];  const float* b1_1 = (const float*)d_in[7];
    const float* W2_1 = (const float*)d_in[8];  const float* b2_1 = (const float*)d_in[9];
    const float* Wih = (const float*)d_in[10];  const float* bih = (const float*)d_in[11];
    const float* Whh = (const float*)d_in[12];  const float* bhh = (const float*)d_in[13];
    const float* fc1W = (const float*)d_in[14]; const float* fc1b = (const float*)d_in[15];
    const float* fc2W = (const float*)d_in[16]; const float* fc2b = (const float*)d_in[17];
    const float* fcLW = (const float*)d_in[18]; const float* fcLb = (const float*)d_in[19];
    const int* edges[2] = {(const int*)d_in[20], (const int*)d_in[21]};
    const int* gid = (const int*)d_in[22];
    float* out = (float*)d_out;

    char* p = (char*)d_ws;
    auto alloc = [&](size_t bytes){ char* r = p; p += (bytes + 255) & ~(size_t)255; return r; };
    u16* XA = (u16*)alloc((size_t)MROW*HPIT*2);
    u16* XB = (u16*)alloc((size_t)MROW*HPIT*2);
    u16* U0 = (u16*)alloc((size_t)MROW*UPIT*2);
    u16* U1 = (u16*)alloc((size_t)MROW*UPIT*2);
    u16* W1b0 = (u16*)alloc(192*WPIT*2);
    u16* W1b1 = (u16*)alloc(192*WPIT*2);
    u16* Wr = (u16*)alloc(192*WPIT*2);
    u16* Wz = (u16*)alloc(192*WPIT*2);
    u16* Un = (u16*)alloc(192*WPIT*2);
    u16* Cb = (u16*)alloc((size_t)6*192*WPIT*2);
    float* tb   = (float*)alloc(10*160*4);
    float* b1t0 = (float*)alloc(160*4);
    float* b1t1 = (float*)alloc(160*4);
    float* fc1p = (float*)alloc(80*160*4);
    float* gbuf = (float*)alloc(GG*150*4);
    int* off0 = (int*)alloc((NN+1)*4);
    int* off1 = (int*)alloc((NN+1)*4);
    int* cur  = (int*)alloc(NN*4);
    int* hist = (int*)alloc(NN*4);
    int* csr0 = (int*)alloc((size_t)EE*4);
    int* csr1 = (int*)alloc((size_t)EE*4);
    (void)alloc(4096);   // tail pad for harmless last-row K-chunk overrun reads
    int* offs[2] = {off0, off1};
    int* csrs[2] = {csr0, csr1};

    // ---- prep ----
    k_splitW<<<120, 256, 0, stream>>>(W1_0, 0, W1b0);
    k_splitW<<<120, 256, 0, stream>>>(W1_1, 0, W1b1);
    k_splitW<<<120, 256, 0, stream>>>(Whh, 0,   Wr);
    k_splitW<<<120, 256, 0, stream>>>(Whh, 150, Wz);
    k_splitW<<<120, 256, 0, stream>>>(Whh, 300, Un);
    k_comp<<<(6*192*160 + 255)/256, 256, 0, stream>>>(Wih, W2_0, W2_1, Cb);
    k_tabs<<<(12*160 + 255)/256, 256, 0, stream>>>(bih, bhh, Wih, b2_0, b2_1, b1_0, b1_1, tb, b1t0, b1t1);
    k_padfc1<<<50, 256, 0, stream>>>(fc1W, fc1p);
    k_inith<<<(NN*152 + 255)/256, 256, 0, stream>>>(nodes, XA);

    // ---- CSR ----
    for (int s=0; s<2; s++){
        hipMemsetAsync(hist, 0, NN*sizeof(int), stream);
        k_hist<<<(EE+255)/256, 256, 0, stream>>>(edges[s], hist);
        k_scan<<<1, 1024, 0, stream>>>(hist, offs[s], cur);
        k_fill<<<(EE+255)/256, 256, 0, stream>>>(edges[s], cur, csrs[s]);
    }

    size_t wsz = (size_t)192*WPIT;
    const u16* Cr0 = Cb + 0*wsz; const u16* Cr1 = Cb + 1*wsz;
    const u16* Cz0 = Cb + 2*wsz; const u16* Cz1 = Cb + 3*wsz;
    const u16* Cn0 = Cb + 4*wsz; const u16* Cn1 = Cb + 5*wsz;

    // ---- message passes ----
    u16* Hc = XA; u16* Hx = XB;
    dim3 gT(MROW/64, 3);
    dim3 gGa((NN+3)/4, 2);
    for (int ps=0; ps<4; ps++){
        u16* yu0 = Hx;                          // u scratch aliases h_next; dead before mega writes Hx
        u16* yu1 = Hx + (size_t)MROW*UPIT;
        k_ugemm2<<<gT, 256, 0, stream>>>(Hc, W1b0, W1b1, b1t0, b1t1, yu0, yu1);
        k_gath2<<<gGa, 256, 0, stream>>>(yu0, yu1, off0, csr0, off1, csr1, U0, U1);
        k_mega<<<gT, 256, 0, stream>>>(Hc, U0, U1, Cr0,Cz0,Cn0, Cr1,Cz1,Cn1,
                                       Wr, Wz, Un, tb, off0, off1, Hx);
        u16* t = Hc; Hc = Hx; Hx = t;
    }

    // ---- readout ----
    hipMemsetAsync(gbuf, 0, GG*150*sizeof(float), stream);
    k_seg<<<(NN+511)/512, 192, 0, stream>>>(Hc, gid, gbuf);
    k_mlp<<<1, 256, 0, stream>>>(gbuf, pt, fc1p, fc1b, fc2W, fc2b, fcLW, fcLb, out);
}

// Round 5
// 2221.679 us; speedup vs baseline: 7.0393x; 1.2066x over previous
//
#include <hip/hip_runtime.h>

typedef unsigned short u16;
typedef unsigned int u32;
typedef __attribute__((ext_vector_type(8))) short s8v;      // 8 bf16
typedef __attribute__((ext_vector_type(8))) _Float16 h8v;   // 8 fp16
typedef __attribute__((ext_vector_type(4))) float f4v;      // C/D frag

#define NN 100000
#define MROW 100096
#define EE 500000
#define GG 16
#define HPIT 304      // h row pitch (u16): [hi 152 | lo 152]
#define UPIT 152      // u/U row pitch (u16): fp16, cols 150/151 carry degrees
#define WPIT 320      // weight row pitch (u16): [hi 160 | lo 160]
#define WMAT (192*WPIT)   // one weight matrix (u16 elems)

__device__ __forceinline__ u16 f2bf(float x){ u32 u=__float_as_uint(x); return (u16)((u + 0x7fffu + ((u>>16)&1u))>>16); }
__device__ __forceinline__ float bf2f(u16 h){ return __uint_as_float(((u32)h)<<16); }
__device__ __forceinline__ u16 f2h(float x){ union{u16 u;_Float16 f;}c; c.f=(_Float16)x; return c.u; }
__device__ __forceinline__ float h2f(u16 b){ union{u16 u;_Float16 f;}c; c.u=b; return (float)c.f; }

#define GLOAD_LDS(gp, lp) \
    __builtin_amdgcn_global_load_lds((const __attribute__((address_space(1))) void*)(gp), \
                                     (__attribute__((address_space(3))) void*)(lp), 16, 0, 0)

// ---------------- hoisted staging helpers ----------------
template<int NI>
__device__ __forceinline__ void stage_a(const u16* base, const int (&off)[NI], int koff,
                                        const int (&lds)[NI], u16* dst){
#pragma unroll
    for (int i=0;i<NI;i++) GLOAD_LDS(base+off[i]+koff, dst+lds[i]);
}
template<int NI>
__device__ __forceinline__ void stage_w(const u16* grp, const int (&off)[NI], int woff,
                                        const int (&lds)[NI], u16* lW){
#pragma unroll
    for (int i=0;i<NI;i++) GLOAD_LDS(grp+off[i]+woff, lW+lds[i]);
}

// one ks-step: 4 A-frags x NW W-frags -> 4*NW MFMA
template<bool ISBF, int NW>
__device__ __forceinline__ void mfstep(const u16* lA_, const u16* lW_, const int (&afo)[4], int wfo, int pstr,
                                       f4v (&X)[4], f4v (&Y)[4], f4v (&Z)[4]){
    s8v af[4];
#pragma unroll
    for (int mi=0;mi<4;mi++) af[mi] = *(const s8v*)(lA_+afo[mi]);
    s8v w0 = *(const s8v*)(lW_+wfo);
    s8v w1 = (NW>1) ? *(const s8v*)(lW_+pstr+wfo) : w0;
    s8v w2 = (NW>2) ? *(const s8v*)(lW_+2*pstr+wfo) : w0;
#pragma unroll
    for (int mi=0;mi<4;mi++){
        if constexpr (ISBF){
            X[mi]=__builtin_amdgcn_mfma_f32_16x16x32_bf16(af[mi],w0,X[mi],0,0,0);
            if (NW>1) Y[mi]=__builtin_amdgcn_mfma_f32_16x16x32_bf16(af[mi],w1,Y[mi],0,0,0);
            if (NW>2) Z[mi]=__builtin_amdgcn_mfma_f32_16x16x32_bf16(af[mi],w2,Z[mi],0,0,0);
        } else {
            X[mi]=__builtin_amdgcn_mfma_f32_16x16x32_f16(*(const h8v*)&af[mi],*(const h8v*)&w0,X[mi],0,0,0);
            if (NW>1) Y[mi]=__builtin_amdgcn_mfma_f32_16x16x32_f16(*(const h8v*)&af[mi],*(const h8v*)&w1,Y[mi],0,0,0);
            if (NW>2) Z[mi]=__builtin_amdgcn_mfma_f32_16x16x32_f16(*(const h8v*)&af[mi],*(const h8v*)&w2,Z[mi],0,0,0);
        }
    }
}

// ---------------- edge-MLP layer 1 (both sets): u_s = lrelu(h @ W1_s^T + b1_s) ----------------
__global__ __launch_bounds__(256,3) void k_ugemm2(const u16* __restrict__ H,
    const u16* __restrict__ W1b,   // 2 mats contiguous: [set0|set1]
    const float* __restrict__ b1t0, const float* __restrict__ b1t1,
    u16* __restrict__ u0, u16* __restrict__ u1)
{
    __shared__ u16 lA0[64*64], lA1[64*64], lW[2*64*64];
    int tid=threadIdx.x, wv=tid>>6, lane=tid&63, lr=lane&15, quad=lane>>4;
    int m0=blockIdx.x*64, n0=blockIdx.y*64;
    // precompute
    int aL64[2], hO64[2];
#pragma unroll
    for (int i=0;i<2;i++){ int s=tid+i*256, row=s>>3, q8=((s&7)^(row&7))<<3;
        aL64[i]=s<<3; hO64[i]=(m0+row)*HPIT+q8; }
    int wL64[4], wO64[4];
#pragma unroll
    for (int i=0;i<4;i++){ int s=tid+i*256, sel=s>>9, rem=s&511, row=rem>>3, q8=((rem&7)^(row&7))<<3;
        wL64[i]=sel*4096+rem*8; wO64[i]=sel*WMAT+(n0+row)*WPIT+q8; }
    int aL32[1], hO32[1];
    { int s=tid, row=s>>2, q8=((s&3)^(row&3))<<3; aL32[0]=s<<3; hO32[0]=(m0+row)*HPIT+q8; }
    int wL32[2], wO32[2];
#pragma unroll
    for (int i=0;i<2;i++){ int s=tid+i*256, sel=s>>8, rem=s&255, row=rem>>2, q8=((rem&3)^(row&3))<<3;
        wL32[i]=sel*2048+rem*8; wO32[i]=sel*WMAT+(n0+row)*WPIT+q8; }
    int aF64[2][4], wF64[2], aF32[4], wF32;
#pragma unroll
    for (int ks=0;ks<2;ks++){
#pragma unroll
        for (int mi=0;mi<4;mi++){ int row=mi*16+lr, ph=(ks*4+quad)^(row&7); aF64[ks][mi]=row*64+ph*8; }
        int wr=wv*16+lr, wp=(ks*4+quad)^(wr&7); wF64[ks]=wr*64+wp*8;
    }
#pragma unroll
    for (int mi=0;mi<4;mi++){ int row=mi*16+lr, ph=quad^(row&3); aF32[mi]=row*32+ph*8; }
    { int wr=wv*16+lr, wp=quad^(wr&3); wF32=wr*32+wp*8; }

    const u16* Hlo = H + 152;
    f4v a0[4]={}, a1[4]={};
#pragma unroll
    for (int kc=0;kc<2;kc++){
        int koff=kc*64;
        __syncthreads();
        stage_a<2>(H,hO64,koff,aL64,lA0);
        stage_w<4>(W1b,wO64,koff,wL64,lW);
        __syncthreads();
#pragma unroll
        for (int ks=0;ks<2;ks++) mfstep<true,2>(lA0,lW,aF64[ks],wF64[ks],4096,a0,a1,a1);
        stage_a<2>(Hlo,hO64,koff,aL64,lA1);
        __syncthreads();
#pragma unroll
        for (int ks=0;ks<2;ks++) mfstep<true,2>(lA1,lW,aF64[ks],wF64[ks],4096,a0,a1,a1);
        __syncthreads();
        stage_w<4>(W1b,wO64,160+koff,wL64,lW);
        __syncthreads();
#pragma unroll
        for (int ks=0;ks<2;ks++) mfstep<true,2>(lA0,lW,aF64[ks],wF64[ks],4096,a0,a1,a1);
    }
    __syncthreads();
    stage_a<1>(H,hO32,128,aL32,lA0);
    stage_w<2>(W1b,wO32,128,wL32,lW);
    __syncthreads();
    mfstep<true,2>(lA0,lW,aF32,wF32,2048,a0,a1,a1);
    stage_a<1>(Hlo,hO32,128,aL32,lA1);
    __syncthreads();
    mfstep<true,2>(lA1,lW,aF32,wF32,2048,a0,a1,a1);
    __syncthreads();
    stage_w<2>(W1b,wO32,288,wL32,lW);
    __syncthreads();
    mfstep<true,2>(lA0,lW,aF32,wF32,2048,a0,a1,a1);

    int c = n0 + wv*16 + lr;
    if (c < 152){
        float bb0=b1t0[c], bb1=b1t1[c];
#pragma unroll
        for (int mi=0;mi<4;mi++)
#pragma unroll
            for (int reg=0;reg<4;reg++){
                int r = m0 + mi*16 + quad*4 + reg;
                if (r >= NN) continue;
                float v0=a0[mi][reg]+bb0; v0 = v0>0.f ? v0 : 0.01f*v0;
                float v1=a1[mi][reg]+bb1; v1 = v1>0.f ? v1 : 0.01f*v1;
                if (c>=150){ v0=0.f; v1=0.f; }
                u0[(size_t)r*UPIT+c]=f2h(v0);
                u1[(size_t)r*UPIT+c]=f2h(v1);
            }
    }
}

// ---------------- fused GRU mega-kernel ----------------
__global__ __launch_bounds__(256,3) void k_mega(const u16* __restrict__ H,
    const u16* __restrict__ U0, const u16* __restrict__ U1,
    const u16* __restrict__ Cb,   // 6 mats: [s][gate r,z,n]
    const u16* __restrict__ Wh,   // 3 mats: Whh gates r,z,n (split)
    const float* __restrict__ tb, u16* __restrict__ Hn)
{
    __shared__ u16 lA0[64*64], lA1[64*64], lW[3*64*64];
    int tid=threadIdx.x, wv=tid>>6, lane=tid&63, lr=lane&15, quad=lane>>4;
    int m0=blockIdx.x*64, n0=blockIdx.y*64;
    int aL64[2], uO64[2], hO64[2];
#pragma unroll
    for (int i=0;i<2;i++){ int s=tid+i*256, row=s>>3, q8=((s&7)^(row&7))<<3;
        aL64[i]=s<<3; uO64[i]=(m0+row)*UPIT+q8; hO64[i]=(m0+row)*HPIT+q8; }
    int wL64[6], wO64[6];
#pragma unroll
    for (int i=0;i<6;i++){ int s=tid+i*256, sel=s>>9, rem=s&511, row=rem>>3, q8=((rem&7)^(row&7))<<3;
        wL64[i]=sel*4096+rem*8; wO64[i]=sel*WMAT+(n0+row)*WPIT+q8; }
    int aL32[1], uO32[1], hO32[1];
    { int s=tid, row=s>>2, q8=((s&3)^(row&3))<<3; aL32[0]=s<<3; uO32[0]=(m0+row)*UPIT+q8; hO32[0]=(m0+row)*HPIT+q8; }
    int wL32[3], wO32[3];
#pragma unroll
    for (int i=0;i<3;i++){ int s=tid+i*256, sel=s>>8, rem=s&255, row=rem>>2, q8=((rem&3)^(row&3))<<3;
        wL32[i]=sel*2048+rem*8; wO32[i]=sel*WMAT+(n0+row)*WPIT+q8; }
    int aF64[2][4], wF64[2], aF32[4], wF32;
#pragma unroll
    for (int ks=0;ks<2;ks++){
#pragma unroll
        for (int mi=0;mi<4;mi++){ int row=mi*16+lr, ph=(ks*4+quad)^(row&7); aF64[ks][mi]=row*64+ph*8; }
        int wr=wv*16+lr, wp=(ks*4+quad)^(wr&7); wF64[ks]=wr*64+wp*8;
    }
#pragma unroll
    for (int mi=0;mi<4;mi++){ int row=mi*16+lr, ph=quad^(row&3); aF32[mi]=row*32+ph*8; }
    { int wr=wv*16+lr, wp=quad^(wr&3); wF32=wr*32+wp*8; }

    f4v aR[4]={}, aZ[4]={}, aI[4]={}, aHh[4]={};
    // ---- u-side (fp16): r,z,in from U0,U1 with composite weights (deg folded at k=150/151) ----
#pragma unroll
    for (int s=0;s<2;s++){
        const u16* U  = s ? U1 : U0;
        const u16* Cg = Cb + (size_t)s*(3*WMAT);
#pragma unroll
        for (int kc=0;kc<2;kc++){
            int koff=kc*64;
            __syncthreads();
            stage_a<2>(U,uO64,koff,aL64,lA0);
            stage_w<6>(Cg,wO64,koff,wL64,lW);
            __syncthreads();
#pragma unroll
            for (int ks=0;ks<2;ks++) mfstep<false,3>(lA0,lW,aF64[ks],wF64[ks],4096,aR,aZ,aI);
            __syncthreads();
            stage_w<6>(Cg,wO64,160+koff,wL64,lW);
            __syncthreads();
#pragma unroll
            for (int ks=0;ks<2;ks++) mfstep<false,3>(lA0,lW,aF64[ks],wF64[ks],4096,aR,aZ,aI);
        }
        __syncthreads();
        stage_a<1>(U,uO32,128,aL32,lA0);
        stage_w<3>(Cg,wO32,128,wL32,lW);
        __syncthreads();
        mfstep<false,3>(lA0,lW,aF32,wF32,2048,aR,aZ,aI);
        __syncthreads();
        stage_w<3>(Cg,wO32,288,wL32,lW);
        __syncthreads();
        mfstep<false,3>(lA0,lW,aF32,wF32,2048,aR,aZ,aI);
    }
    // ---- h-side (split-bf16): r,z,hn ----
    const u16* Hlo = H + 152;
#pragma unroll
    for (int kc=0;kc<2;kc++){
        int koff=kc*64;
        __syncthreads();
        stage_a<2>(H,hO64,koff,aL64,lA0);
        stage_w<6>(Wh,wO64,koff,wL64,lW);
        __syncthreads();
#pragma unroll
        for (int ks=0;ks<2;ks++) mfstep<true,3>(lA0,lW,aF64[ks],wF64[ks],4096,aR,aZ,aHh);
        stage_a<2>(Hlo,hO64,koff,aL64,lA1);
        __syncthreads();
#pragma unroll
        for (int ks=0;ks<2;ks++) mfstep<true,3>(lA1,lW,aF64[ks],wF64[ks],4096,aR,aZ,aHh);
        __syncthreads();
        stage_w<6>(Wh,wO64,160+koff,wL64,lW);
        __syncthreads();
#pragma unroll
        for (int ks=0;ks<2;ks++) mfstep<true,3>(lA0,lW,aF64[ks],wF64[ks],4096,aR,aZ,aHh);
    }
    __syncthreads();
    stage_a<1>(H,hO32,128,aL32,lA0);
    stage_w<3>(Wh,wO32,128,wL32,lW);
    __syncthreads();
    mfstep<true,3>(lA0,lW,aF32,wF32,2048,aR,aZ,aHh);
    stage_a<1>(Hlo,hO32,128,aL32,lA1);
    __syncthreads();
    mfstep<true,3>(lA1,lW,aF32,wF32,2048,aR,aZ,aHh);
    __syncthreads();
    stage_w<3>(Wh,wO32,288,wL32,lW);
    __syncthreads();
    mfstep<true,3>(lA0,lW,aF32,wF32,2048,aR,aZ,aHh);

    // ---- GRU epilogue ----
    int c = n0 + wv*16 + lr;
    if (c < 152){
        float bR=tb[c], bZ=tb[160+c], bI=tb[320+c], bHn=tb[480+c];
#pragma unroll
        for (int mi=0;mi<4;mi++)
#pragma unroll
            for (int reg=0;reg<4;reg++){
                int r = m0 + mi*16 + quad*4 + reg;
                if (r >= NN) continue;
                float pr=aR[mi][reg]+bR, pz=aZ[mi][reg]+bZ, pi=aI[mi][reg]+bI, ph_=aHh[mi][reg]+bHn;
                float rg = 1.f/(1.f+__expf(-pr));
                float zg = 1.f/(1.f+__expf(-pz));
                float e2 = __expf(2.f*(pi + rg*ph_));
                float n  = 1.f - 2.f/(e2+1.f);
                float hold = bf2f(H[(size_t)r*HPIT+c]) + bf2f(H[(size_t)r*HPIT+152+c]);
                float o = (1.f-zg)*n + zg*hold;
                if (c>=150) o = 0.f;
                u16 hi = f2bf(o);
                Hn[(size_t)r*HPIT+c] = hi;
                Hn[(size_t)r*HPIT+152+c] = f2bf(o - bf2f(hi));
            }
    }
}

// ---------------- prep kernels ----------------
__global__ void k_splitW(const float* __restrict__ src, int rowoff, u16* __restrict__ dst){
    int idx = blockIdx.x*256 + threadIdx.x;     // 192*160
    if (idx >= 192*160) return;
    int r = idx/160, c = idx - r*160;
    float x = (r<150 && c<150) ? src[(size_t)(rowoff+r)*150 + c] : 0.f;
    u16 hi = f2bf(x);
    dst[(size_t)r*WPIT + c] = hi;
    dst[(size_t)r*WPIT + 160 + c] = f2bf(x - bf2f(hi));
}

// composite C[s*3+g] = Wih_g @ W2_s (cols 0..149) ; col 150 (s=0) / 151 (s=1) = Wih_g @ b2_s
__global__ void k_comp(const float* __restrict__ Wih, const float* __restrict__ W2_0,
                       const float* __restrict__ W2_1, const float* __restrict__ b2_0,
                       const float* __restrict__ b2_1, u16* __restrict__ Cb){
    int idx = blockIdx.x*256 + threadIdx.x;     // 6*192*160
    if (idx >= 6*192*160) return;
    int mat = idx/(192*160), rem = idx - mat*(192*160);
    int o = rem/160, c = rem - o*160;
    int s = mat/3, g = mat - s*3;
    float v = 0.f;
    if (o < 150){
        const float* wrow = Wih + (size_t)(g*150+o)*150;
        if (c < 150){
            const float* W2 = s ? W2_1 : W2_0;
            for (int j=0;j<150;j++) v += wrow[j] * W2[(size_t)j*150 + c];
        } else if (c==150 && s==0){
            for (int j=0;j<150;j++) v += wrow[j] * b2_0[j];
        } else if (c==151 && s==1){
            for (int j=0;j<150;j++) v += wrow[j] * b2_1[j];
        }
    }
    u16* D = Cb + (size_t)mat*WMAT;
    union{u16 u;_Float16 f;} h1,h2;
    h1.f = (_Float16)v;
    h2.f = (_Float16)(v - (float)h1.f);
    D[(size_t)o*WPIT + c] = h1.u;
    D[(size_t)o*WPIT + 160 + c] = h2.u;
}

__global__ void k_tabs(const float* bih,const float* bhh,
                       const float* b1_0,const float* b1_1,
                       float* tb, float* b1t0, float* b1t1){
    int idx = blockIdx.x*256 + threadIdx.x;     // 6*160
    if (idx >= 6*160) return;
    int t = idx/160, c = idx - t*160;
    float v = 0.f;
    if (c < 150){
        if (t==0) v = bih[c]+bhh[c];
        else if (t==1) v = bih[150+c]+bhh[150+c];
        else if (t==2) v = bih[300+c];
        else if (t==3) v = bhh[300+c];
        else if (t==4) v = b1_0[c];
        else v = b1_1[c];
    }
    if (t<4) tb[t*160+c]=v;
    else if (t==4) b1t0[c]=v;
    else b1t1[c]=v;
}

__global__ void k_padfc1(const float* __restrict__ s, float* __restrict__ d){
    int idx = blockIdx.x*256 + threadIdx.x;     // 80*160
    if (idx >= 80*160) return;
    int r = idx/160, c = idx - r*160;
    d[idx] = (c<151) ? s[r*151 + c] : 0.f;
}

__global__ void k_inith(const float* __restrict__ nodes, u16* __restrict__ H){
    int idx = blockIdx.x*256 + threadIdx.x;     // NN*152
    if (idx >= NN*152) return;
    int m = idx/152, c = idx - m*152;
    float x = (c<150) ? nodes[(size_t)m*150 + c] : 0.f;
    u16 hi = f2bf(x);
    H[(size_t)m*HPIT + c] = hi;
    H[(size_t)m*HPIT + 152 + c] = f2bf(x - bf2f(hi));
}

// ---------------- CSR build ----------------
__global__ void k_hist(const int* __restrict__ edges, int* __restrict__ cnt){
    int e = blockIdx.x*256 + threadIdx.x;
    if (e >= EE) return;
    atomicAdd(&cnt[edges[2*e]], 1);
}

__global__ __launch_bounds__(1024) void k_scan(const int* __restrict__ cnt,
                                               int* __restrict__ off, int* __restrict__ cur){
    __shared__ int sd[1024];
    __shared__ int s_run;
    int t = threadIdx.x;
    if (t==0) s_run = 0;
    __syncthreads();
    for (int base=0; base<NN; base+=8192){
        int i0 = base + t*8;
        int v[8]; int s = 0;
#pragma unroll
        for (int u=0; u<8; u++){ int i=i0+u; v[u]=(i<NN)?cnt[i]:0; s+=v[u]; }
        sd[t]=s;
        __syncthreads();
        int runbase = s_run;
        for (int ofs=1; ofs<1024; ofs<<=1){
            int y=0;
            if (t>=ofs) y=sd[t-ofs];
            __syncthreads();
            if (t>=ofs) sd[t]+=y;
            __syncthreads();
        }
        int excl = runbase + sd[t] - s;
#pragma unroll
        for (int u=0; u<8; u++){
            int i=i0+u;
            if (i<NN){ off[i]=excl; cur[i]=excl; excl+=v[u]; }
        }
        __syncthreads();
        if (t==1023) s_run = runbase + sd[1023];
        __syncthreads();
    }
    if (t==0) off[NN] = s_run;
}

__global__ void k_fill(const int* __restrict__ edges, int* __restrict__ cur, int* __restrict__ csr){
    int e = blockIdx.x*256 + threadIdx.x;
    if (e >= EE) return;
    int dst = edges[2*e], src = edges[2*e+1];
    int pos = atomicAdd(&cur[dst], 1);
    csr[pos] = src;
}

// ---------------- gather; writes degree into cols 150/151 ----------------
__global__ void k_gath2(const u16* __restrict__ u0, const u16* __restrict__ u1,
                        const int* __restrict__ off0, const int* __restrict__ csr0,
                        const int* __restrict__ off1, const int* __restrict__ csr1,
                        u16* __restrict__ U0, u16* __restrict__ U1){
    int d = blockIdx.x*4 + (threadIdx.x>>6);
    if (d >= NN) return;
    int lane = threadIdx.x & 63;
    const u16* u = blockIdx.y ? u1 : u0;
    const int* off = blockIdx.y ? off1 : off0;
    const int* csr = blockIdx.y ? csr1 : csr0;
    u16* U = blockIdx.y ? U1 : U0;
    int e0 = off[d], e1 = off[d+1];
    float a0=0.f, a1=0.f, a2=0.f;
    for (int e=e0; e<e1; e++){
        const u16* r = u + (size_t)csr[e]*UPIT;
        a0 += h2f(r[lane]);
        a1 += h2f(r[lane+64]);
        if (lane < 24) a2 += h2f(r[lane+128]);
    }
    if (lane >= 22) a2 = (float)(e1 - e0);    // lanes 22,23 -> cols 150,151 = degree
    U[(size_t)d*UPIT + lane]      = f2h(a0);
    U[(size_t)d*UPIT + lane + 64] = f2h(a1);
    if (lane < 24) U[(size_t)d*UPIT + lane + 128] = f2h(a2);
}

// ---------------- segment sum + readout ----------------
__global__ void k_seg(const u16* __restrict__ H, const int* __restrict__ gid, float* __restrict__ g){
    int f = threadIdx.x;
    if (f >= 150) return;
    int i0 = blockIdx.x*512;
    int i1 = i0 + 512; if (i1 > NN) i1 = NN;
    float acc = 0.f;
    int cg = gid[i0];
    for (int i=i0; i<i1; i++){
        int gg = gid[i];
        if (gg != cg){ atomicAdd(&g[cg*150+f], acc); acc=0.f; cg=gg; }
        acc += bf2f(H[(size_t)i*HPIT + f]) + bf2f(H[(size_t)i*HPIT + 152 + f]);
    }
    atomicAdd(&g[cg*150+f], acc);
}

__global__ void k_mlp(const float* __restrict__ g, const float* __restrict__ pt,
                      const float* __restrict__ fc1p, const float* __restrict__ fc1b,
                      const float* __restrict__ fc2W, const float* __restrict__ fc2b,
                      const float* __restrict__ fcLW, const float* __restrict__ fcLb,
                      float* __restrict__ out){
    __shared__ float X[GG][152];
    __shared__ float Y[GG][80];
    __shared__ float Z[GG][80];
    int t = threadIdx.x;
    for (int idx=t; idx<GG*152; idx+=256){
        int gi=idx/152, c=idx-gi*152;
        float v = 0.f;
        if (c < 150){
            float lg = logf(g[gi*150+c]);
            if (lg != lg) lg = 0.f;
            v = fmaxf(lg, 0.f);
        } else if (c == 150) v = pt[gi];
        X[gi][c] = v;
    }
    __syncthreads();
    for (int idx=t; idx<GG*80; idx+=256){
        int gi=idx/80, o=idx-gi*80;
        float acc = fc1b[o];
        for (int k=0;k<151;k++) acc = fmaf(X[gi][k], fc1p[o*160+k], acc);
        Y[gi][o] = acc>0.f ? acc : 0.01f*acc;
    }
    __syncthreads();
    for (int idx=t; idx<GG*80; idx+=256){
        int gi=idx/80, o=idx-gi*80;
        float acc = fc2b[o];
        for (int k=0;k<80;k++) acc = fmaf(Y[gi][k], fc2W[o*80+k], acc);
        Z[gi][o] = acc>0.f ? acc : 0.01f*acc;
    }
    __syncthreads();
    for (int idx=t; idx<GG*10; idx+=256){
        int gi=idx/10, o=idx-gi*10;
        float acc = fcLb[o];
        for (int k=0;k<80;k++) acc = fmaf(Z[gi][k], fcLW[o*80+k], acc);
        out[idx] = acc;
    }
}

// ---------------- host ----------------
extern "C" void kernel_launch(void* const* d_in, const int* in_sizes, int n_in,
                              void* d_out, int out_size, void* d_ws, size_t ws_size,
                              hipStream_t stream) {
    const float* nodes = (const float*)d_in[0];
    const float* pt    = (const float*)d_in[1];
    const float* W1_0 = (const float*)d_in[2];  const float* b1_0 = (const float*)d_in[3];
    const float* W2_0 = (const float*)d_in[4];  const float* b2_0 = (const float*)d_in[5];
    const float* W1_1 = (const float*)d_in[6];  const float* b1_1 = (const float*)d_in[7];
    const float* W2_1 = (const float*)d_in[8];  const float* b2_1 = (const float*)d_in[9];
    const float* Wih = (const float*)d_in[10];  const float* bih = (const float*)d_in[11];
    const float* Whh = (const float*)d_in[12];  const float* bhh = (const float*)d_in[13];
    const float* fc1W = (const float*)d_in[14]; const float* fc1b = (const float*)d_in[15];
    const float* fc2W = (const float*)d_in[16]; const float* fc2b = (const float*)d_in[17];
    const float* fcLW = (const float*)d_in[18]; const float* fcLb = (const float*)d_in[19];
    const int* edges[2] = {(const int*)d_in[20], (const int*)d_in[21]};
    const int* gid = (const int*)d_in[22];
    float* out = (float*)d_out;

    char* p = (char*)d_ws;
    auto alloc = [&](size_t bytes){ char* r = p; p += (bytes + 255) & ~(size_t)255; return r; };
    u16* XA = (u16*)alloc((size_t)MROW*HPIT*2);
    u16* XB = (u16*)alloc((size_t)MROW*HPIT*2);
    u16* U0 = (u16*)alloc((size_t)MROW*UPIT*2);
    u16* U1 = (u16*)alloc((size_t)MROW*UPIT*2);
    u16* W1b = (u16*)alloc((size_t)2*WMAT*2);    // [set0|set1] split-bf16
    u16* Wh  = (u16*)alloc((size_t)3*WMAT*2);    // Whh gates r,z,n split-bf16
    u16* Cb  = (u16*)alloc((size_t)6*WMAT*2);    // composite, fp16-split
    float* tb   = (float*)alloc(4*160*4);
    float* b1t0 = (float*)alloc(160*4);
    float* b1t1 = (float*)alloc(160*4);
    float* fc1p = (float*)alloc(80*160*4);
    float* gbuf = (float*)alloc(GG*150*4);
    int* off0 = (int*)alloc((NN+1)*4);
    int* off1 = (int*)alloc((NN+1)*4);
    int* cur  = (int*)alloc(NN*4);
    int* hist = (int*)alloc(NN*4);
    int* csr0 = (int*)alloc((size_t)EE*4);
    int* csr1 = (int*)alloc((size_t)EE*4);
    (void)alloc(4096);   // tail pad for harmless last-row K-chunk overrun reads
    int* offs[2] = {off0, off1};
    int* csrs[2] = {csr0, csr1};

    // ---- prep ----
    k_splitW<<<120, 256, 0, stream>>>(W1_0, 0, W1b);
    k_splitW<<<120, 256, 0, stream>>>(W1_1, 0, W1b + WMAT);
    k_splitW<<<120, 256, 0, stream>>>(Whh, 0,   Wh);
    k_splitW<<<120, 256, 0, stream>>>(Whh, 150, Wh + WMAT);
    k_splitW<<<120, 256, 0, stream>>>(Whh, 300, Wh + 2*WMAT);
    k_comp<<<(6*192*160 + 255)/256, 256, 0, stream>>>(Wih, W2_0, W2_1, b2_0, b2_1, Cb);
    k_tabs<<<4, 256, 0, stream>>>(bih, bhh, b1_0, b1_1, tb, b1t0, b1t1);
    k_padfc1<<<50, 256, 0, stream>>>(fc1W, fc1p);
    k_inith<<<(NN*152 + 255)/256, 256, 0, stream>>>(nodes, XA);

    // ---- CSR ----
    for (int s=0; s<2; s++){
        hipMemsetAsync(hist, 0, NN*sizeof(int), stream);
        k_hist<<<(EE+255)/256, 256, 0, stream>>>(edges[s], hist);
        k_scan<<<1, 1024, 0, stream>>>(hist, offs[s], cur);
        k_fill<<<(EE+255)/256, 256, 0, stream>>>(edges[s], cur, csrs[s]);
    }

    // ---- message passes ----
    u16* Hc = XA; u16* Hx = XB;
    dim3 gT(MROW/64, 3);
    dim3 gGa((NN+3)/4, 2);
    for (int ps=0; ps<4; ps++){
        u16* yu0 = Hx;                          // u scratch aliases h_next; dead before mega writes Hx
        u16* yu1 = Hx + (size_t)MROW*UPIT;
        k_ugemm2<<<gT, 256, 0, stream>>>(Hc, W1b, b1t0, b1t1, yu0, yu1);
        k_gath2<<<gGa, 256, 0, stream>>>(yu0, yu1, off0, csr0, off1, csr1, U0, U1);
        k_mega<<<gT, 256, 0, stream>>>(Hc, U0, U1, Cb, Wh, tb, Hx);
        u16* t = Hc; Hc = Hx; Hx = t;
    }

    // ---- readout ----
    hipMemsetAsync(gbuf, 0, GG*150*sizeof(float), stream);
    k_seg<<<(NN+511)/512, 192, 0, stream>>>(Hc, gid, gbuf);
    k_mlp<<<1, 256, 0, stream>>>(gbuf, pt, fc1p, fc1b, fc2W, fc2b, fcLW, fcLb, out);
}